// Round 11
// baseline (505.606 us; speedup 1.0000x reference)
//
#include <hip/hip_runtime.h>
#include <hip/hip_bf16.h>
#include <math.h>
#include <stdint.h>

typedef unsigned short u16;
typedef unsigned int u32;
typedef __attribute__((ext_vector_type(8))) short short8;   // 8 bf16 = 4 VGPRs (MFMA A/B frag)
typedef __attribute__((ext_vector_type(4))) float f32x4;    // MFMA C/D frag

__device__ __forceinline__ float b2f(u16 u) {
  union { u32 i; float f; } v; v.i = ((u32)u) << 16; return v.f;
}
__device__ __forceinline__ u16 f2b(float f) {
  union { float f; u32 i; } v; v.f = f;
  return (u16)((v.i + 0x7FFFu + ((v.i >> 16) & 1u)) >> 16);  // RNE
}

// async global->LDS DMA, 16B per lane; LDS dest = wave-uniform base + lane*16B
__device__ __forceinline__ void gload_lds16(const u16* g, u16* l) {
  __builtin_amdgcn_global_load_lds((const __attribute__((address_space(1))) void*)g,
                                   (__attribute__((address_space(3))) void*)l, 16, 0, 0);
}

#define LD8(p) (*(const short8*)(p))
#define MFMA_BF16 __builtin_amdgcn_mfma_f32_16x16x32_bf16

// ---------------- fused transpose+convert: fp32 (K x N) -> bf16 (N x K) ----------------
__global__ __launch_bounds__(256) void transpose_k(const float* __restrict__ in,
                                                   u16* __restrict__ out, int K, int N) {
  __shared__ u16 tile[32][33];
  int n0 = blockIdx.x * 32, k0 = blockIdx.y * 32;
  int tx = threadIdx.x & 31, ty = threadIdx.x >> 5;
  #pragma unroll
  for (int i = ty; i < 32; i += 8)
    tile[i][tx] = f2b(in[(size_t)(k0 + i) * N + n0 + tx]);
  __syncthreads();
  #pragma unroll
  for (int i = ty; i < 32; i += 8)
    out[(size_t)(n0 + i) * K + k0 + tx] = tile[tx][i];
}

// ---------------- concat 3 x 1024 fp32 biases ----------------
__global__ __launch_bounds__(256) void cat3_k(const float* __restrict__ a, const float* __restrict__ b,
                                              const float* __restrict__ c, float* __restrict__ o) {
  int i = blockIdx.x * 256 + threadIdx.x;
  o[i] = i < 1024 ? a[i] : (i < 2048 ? b[i - 1024] : c[i - 2048]);
}

// ---------------- per-head V transpose from strided qkv: v[s][2048+h*64+d] -> vt[(bh*64+d)][s] ----------------
__global__ __launch_bounds__(256) void vtrans_k(const u16* __restrict__ qkv, u16* __restrict__ vt) {
  __shared__ u16 tile[32][33];
  int bh = blockIdx.y, b = bh >> 4, h = bh & 15;
  int s0 = (blockIdx.x & 31) * 32, d0 = (blockIdx.x >> 5) * 32;
  int tx = threadIdx.x & 31, ty = threadIdx.x >> 5;
  #pragma unroll
  for (int i = ty; i < 32; i += 8)
    tile[i][tx] = qkv[(size_t)(b * 1024 + s0 + i) * 3072 + 2048 + h * 64 + d0 + tx];
  __syncthreads();
  #pragma unroll
  for (int i = ty; i < 32; i += 8)
    vt[(size_t)(bh * 64 + d0 + i) * 1024 + s0 + tx] = tile[tx][i];
}

// ---------------- LayerNorm over D=1024, one block per row; FP32IN: x fp32 vs bf16 ----------------
template<int FP32IN>
__global__ __launch_bounds__(256) void ln_k(const void* __restrict__ xv, const float* __restrict__ g,
                                            const float* __restrict__ be, u16* __restrict__ out) {
  int row = blockIdx.x, t = threadIdx.x;
  float f0, f1, f2, f3;
  if (FP32IN) {
    const float* xr = (const float*)xv + (size_t)row * 1024;
    float4 x4 = *(const float4*)(xr + t * 4);
    f0 = x4.x; f1 = x4.y; f2 = x4.z; f3 = x4.w;
  } else {
    const u16* xr = (const u16*)xv + (size_t)row * 1024;
    ushort4 x4 = *(const ushort4*)(xr + t * 4);
    f0 = b2f(x4.x); f1 = b2f(x4.y); f2 = b2f(x4.z); f3 = b2f(x4.w);
  }
  float s = f0 + f1 + f2 + f3;
  float ss = f0 * f0 + f1 * f1 + f2 * f2 + f3 * f3;
  #pragma unroll
  for (int off = 32; off > 0; off >>= 1) { s += __shfl_down(s, off); ss += __shfl_down(ss, off); }
  __shared__ float sb[4], ssb[4];
  if ((t & 63) == 0) { sb[t >> 6] = s; ssb[t >> 6] = ss; }
  __syncthreads();
  s = sb[0] + sb[1] + sb[2] + sb[3];
  ss = ssb[0] + ssb[1] + ssb[2] + ssb[3];
  float mu = s * (1.0f / 1024.0f);
  float var = ss * (1.0f / 1024.0f) - mu * mu;
  float rstd = rsqrtf(var + 1e-5f);
  float4 gv = *(const float4*)(g + t * 4);
  float4 bv = *(const float4*)(be + t * 4);
  ushort4 o;
  o.x = f2b((f0 - mu) * rstd * gv.x + bv.x);
  o.y = f2b((f1 - mu) * rstd * gv.y + bv.y);
  o.z = f2b((f2 - mu) * rstd * gv.z + bv.z);
  o.w = f2b((f3 - mu) * rstd * gv.w + bv.w);
  *(ushort4*)(out + (size_t)row * 1024 + t * 4) = o;
}

// ======================= gemm256_k: BK=64 4-phase + COUNTED waits (QKV + FFN1) =================
// r11: half-tile-granular staging (m201 style) turns the per-tile vmcnt(0) drain into counted
// vmcnt(2) waits. Tile split into 4 units of 2 gloads/wave (interleaved 8-row slabs, R=w*8+ofs):
//   B-h0 = B rows 0-127   (staged P0, read P0/P2 of next tile)
//   B-h1 = B rows 128-255 (staged P1, read P0/P2)
//   A-band0 = A rows {0-63,128-191}  (staged P2, read P0/P2: frags a0-3 for both wm)
//   A-band1 = A rows {64-127,192-255}(staged P3, read P1/P3: frags a4-7)
// Queue accounting (per wave, issue order = retirement order):
//   end-P0: outstanding [A-b1(t)(2), B-h0(t+1)(2)] -> vmcnt(2) retires A-b1(t) (guards P1's
//           ds_reads; cross-wave via the following barrier). Tail tile: vmcnt(0).
//   end-P3: outstanding [B-h0,B-h1,A-b0,A-b1](t+1)=8 -> vmcnt(2) retires B+A-b0 (all P0(t+1)
//           needs); A-b1(t+1) stays in flight. NEVER vmcnt(0) in steady state.
// WAR: each unit's target (buf^1) was last read >=2 barriers earlier (B halves at P2(t-1),
// A bands at P2/P3(t-1)). Swizzle unchanged: phys chunk = logical ^ (row&7), 0 conflicts.
template<int ACT, int RESID, int OUTF32>
__global__ __launch_bounds__(512, 2) void gemm256_k(const u16* __restrict__ A, const u16* __restrict__ Bt,
                                                    const float* __restrict__ bias, const void* __restrict__ resid,
                                                    void* __restrict__ Cv, int M, int N, int K, int ldc) {
  __shared__ u16 As[2][256 * 64];   // 2 x 32KB
  __shared__ u16 Bs[2][256 * 64];   // 2 x 32KB
  int Ny = N >> 8;
  int lin = blockIdx.y * 32 + blockIdx.x;
  int c8 = lin & 7, sblk = lin >> 3;
  int mq = sblk / Ny;
  int m0 = ((mq << 3) | c8) << 8;
  int n0 = (sblk - mq * Ny) << 8;
  int t = threadIdx.x;
  int wave = t >> 6, lane = t & 63, quad = lane >> 4, l16 = lane & 15;
  int wm = (wave >> 2) << 7;            // 0 | 128
  int wn = (wave & 3) << 6;             // 0..192
  f32x4 acc[8][4] = {};
  int lrow = lane >> 3;                        // 0..7
  int lchunk = (lane & 7) ^ lrow;              // src chunk = logical ^ (row&7)
  const u16* AbU = A + (size_t)(m0 + lrow) * K + lchunk * 8;   // + R*K selects 8-row unit
  const u16* BbU = Bt + (size_t)(n0 + lrow) * K + lchunk * 8;
  const int w8 = wave * 8;                     // wave's unit offset within each 64-row band
  const int x7 = l16 & 7;
  const int rdA = (wm + l16) * 64;             // + i*1024 + cswz
  const int rdB = (wn + l16) * 64;             // + j*1024 + cswz
  const int cz0 = (quad ^ x7) * 8;             // kk=0: logical chunk = quad
  const int cz1 = ((4 + quad) ^ x7) * 8;       // kk=1: logical chunk = 4+quad
  const int niter = K >> 6;
  // ---- prologue: tile 0 -> buf0, canonical unit order [B-h0, B-h1, A-b0, A-b1] ----
  gload_lds16(BbU + (size_t)(w8) * K,        &Bs[0][(w8) * 64]);
  gload_lds16(BbU + (size_t)(64 + w8) * K,   &Bs[0][(64 + w8) * 64]);
  gload_lds16(BbU + (size_t)(128 + w8) * K,  &Bs[0][(128 + w8) * 64]);
  gload_lds16(BbU + (size_t)(192 + w8) * K,  &Bs[0][(192 + w8) * 64]);
  gload_lds16(AbU + (size_t)(w8) * K,        &As[0][(w8) * 64]);
  gload_lds16(AbU + (size_t)(128 + w8) * K,  &As[0][(128 + w8) * 64]);
  gload_lds16(AbU + (size_t)(64 + w8) * K,   &As[0][(64 + w8) * 64]);
  gload_lds16(AbU + (size_t)(192 + w8) * K,  &As[0][(192 + w8) * 64]);
  asm volatile("s_waitcnt vmcnt(2)" ::: "memory");   // B + A-band0 landed; A-band1 in flight
  __builtin_amdgcn_s_barrier();
  __builtin_amdgcn_sched_barrier(0);
  for (int tt = 0; tt < niter; tt++) {
    int buf = tt & 1;
    const bool pf = (tt + 1 < niter);
    const int kpf = (tt + 1) << 6;
    const u16* Ac = &As[buf][0];
    const u16* Bc = &Bs[buf][0];
    u16* Aw = &As[buf ^ 1][0];
    u16* Bw = &Bs[buf ^ 1][0];
    short8 a0, a1, a2, a3, a4, a5, a6, a7, b0, b1, b2, b3;
    // ---------- P0: kk=0 i0-3 (A-band0) + all b ; stage B-h0(tt+1) ----------
    a0 = LD8(Ac + rdA + cz0);
    a1 = LD8(Ac + rdA + 1024 + cz0);
    a2 = LD8(Ac + rdA + 2048 + cz0);
    a3 = LD8(Ac + rdA + 3072 + cz0);
    b0 = LD8(Bc + rdB + cz0);
    b1 = LD8(Bc + rdB + 1024 + cz0);
    b2 = LD8(Bc + rdB + 2048 + cz0);
    b3 = LD8(Bc + rdB + 3072 + cz0);
    if (pf) {
      gload_lds16(BbU + kpf + (size_t)(w8) * K,      Bw + (w8) * 64);
      gload_lds16(BbU + kpf + (size_t)(64 + w8) * K, Bw + (64 + w8) * 64);
    }
    __builtin_amdgcn_s_barrier();
    asm volatile("s_waitcnt lgkmcnt(0)" ::: "memory");
    __builtin_amdgcn_sched_barrier(0);
    __builtin_amdgcn_s_setprio(1);
    acc[0][0] = MFMA_BF16(a0, b0, acc[0][0], 0, 0, 0);
    acc[0][1] = MFMA_BF16(a0, b1, acc[0][1], 0, 0, 0);
    acc[0][2] = MFMA_BF16(a0, b2, acc[0][2], 0, 0, 0);
    acc[0][3] = MFMA_BF16(a0, b3, acc[0][3], 0, 0, 0);
    acc[1][0] = MFMA_BF16(a1, b0, acc[1][0], 0, 0, 0);
    acc[1][1] = MFMA_BF16(a1, b1, acc[1][1], 0, 0, 0);
    acc[1][2] = MFMA_BF16(a1, b2, acc[1][2], 0, 0, 0);
    acc[1][3] = MFMA_BF16(a1, b3, acc[1][3], 0, 0, 0);
    acc[2][0] = MFMA_BF16(a2, b0, acc[2][0], 0, 0, 0);
    acc[2][1] = MFMA_BF16(a2, b1, acc[2][1], 0, 0, 0);
    acc[2][2] = MFMA_BF16(a2, b2, acc[2][2], 0, 0, 0);
    acc[2][3] = MFMA_BF16(a2, b3, acc[2][3], 0, 0, 0);
    acc[3][0] = MFMA_BF16(a3, b0, acc[3][0], 0, 0, 0);
    acc[3][1] = MFMA_BF16(a3, b1, acc[3][1], 0, 0, 0);
    acc[3][2] = MFMA_BF16(a3, b2, acc[3][2], 0, 0, 0);
    acc[3][3] = MFMA_BF16(a3, b3, acc[3][3], 0, 0, 0);
    __builtin_amdgcn_s_setprio(0);
    if (pf) { asm volatile("s_waitcnt vmcnt(2)" ::: "memory"); }   // A-band1(tt) landed
    else    { asm volatile("s_waitcnt vmcnt(0)" ::: "memory"); }
    __builtin_amdgcn_s_barrier();
    __builtin_amdgcn_sched_barrier(0);
    // ---------- P1: kk=0 i4-7 (A-band1) ; stage B-h1(tt+1) ----------
    a4 = LD8(Ac + rdA + 4096 + cz0);
    a5 = LD8(Ac + rdA + 5120 + cz0);
    a6 = LD8(Ac + rdA + 6144 + cz0);
    a7 = LD8(Ac + rdA + 7168 + cz0);
    if (pf) {
      gload_lds16(BbU + kpf + (size_t)(128 + w8) * K, Bw + (128 + w8) * 64);
      gload_lds16(BbU + kpf + (size_t)(192 + w8) * K, Bw + (192 + w8) * 64);
    }
    __builtin_amdgcn_s_barrier();
    asm volatile("s_waitcnt lgkmcnt(0)" ::: "memory");
    __builtin_amdgcn_sched_barrier(0);
    __builtin_amdgcn_s_setprio(1);
    acc[4][0] = MFMA_BF16(a4, b0, acc[4][0], 0, 0, 0);
    acc[4][1] = MFMA_BF16(a4, b1, acc[4][1], 0, 0, 0);
    acc[4][2] = MFMA_BF16(a4, b2, acc[4][2], 0, 0, 0);
    acc[4][3] = MFMA_BF16(a4, b3, acc[4][3], 0, 0, 0);
    acc[5][0] = MFMA_BF16(a5, b0, acc[5][0], 0, 0, 0);
    acc[5][1] = MFMA_BF16(a5, b1, acc[5][1], 0, 0, 0);
    acc[5][2] = MFMA_BF16(a5, b2, acc[5][2], 0, 0, 0);
    acc[5][3] = MFMA_BF16(a5, b3, acc[5][3], 0, 0, 0);
    acc[6][0] = MFMA_BF16(a6, b0, acc[6][0], 0, 0, 0);
    acc[6][1] = MFMA_BF16(a6, b1, acc[6][1], 0, 0, 0);
    acc[6][2] = MFMA_BF16(a6, b2, acc[6][2], 0, 0, 0);
    acc[6][3] = MFMA_BF16(a6, b3, acc[6][3], 0, 0, 0);
    acc[7][0] = MFMA_BF16(a7, b0, acc[7][0], 0, 0, 0);
    acc[7][1] = MFMA_BF16(a7, b1, acc[7][1], 0, 0, 0);
    acc[7][2] = MFMA_BF16(a7, b2, acc[7][2], 0, 0, 0);
    acc[7][3] = MFMA_BF16(a7, b3, acc[7][3], 0, 0, 0);
    __builtin_amdgcn_s_setprio(0);
    __builtin_amdgcn_s_barrier();
    __builtin_amdgcn_sched_barrier(0);
    // ---------- P2: kk=1 i0-3 + all b ; stage A-band0(tt+1) ----------
    a0 = LD8(Ac + rdA + cz1);
    a1 = LD8(Ac + rdA + 1024 + cz1);
    a2 = LD8(Ac + rdA + 2048 + cz1);
    a3 = LD8(Ac + rdA + 3072 + cz1);
    b0 = LD8(Bc + rdB + cz1);
    b1 = LD8(Bc + rdB + 1024 + cz1);
    b2 = LD8(Bc + rdB + 2048 + cz1);
    b3 = LD8(Bc + rdB + 3072 + cz1);
    if (pf) {
      gload_lds16(AbU + kpf + (size_t)(w8) * K,       Aw + (w8) * 64);
      gload_lds16(AbU + kpf + (size_t)(128 + w8) * K, Aw + (128 + w8) * 64);
    }
    __builtin_amdgcn_s_barrier();
    asm volatile("s_waitcnt lgkmcnt(0)" ::: "memory");
    __builtin_amdgcn_sched_barrier(0);
    __builtin_amdgcn_s_setprio(1);
    acc[0][0] = MFMA_BF16(a0, b0, acc[0][0], 0, 0, 0);
    acc[0][1] = MFMA_BF16(a0, b1, acc[0][1], 0, 0, 0);
    acc[0][2] = MFMA_BF16(a0, b2, acc[0][2], 0, 0, 0);
    acc[0][3] = MFMA_BF16(a0, b3, acc[0][3], 0, 0, 0);
    acc[1][0] = MFMA_BF16(a1, b0, acc[1][0], 0, 0, 0);
    acc[1][1] = MFMA_BF16(a1, b1, acc[1][1], 0, 0, 0);
    acc[1][2] = MFMA_BF16(a1, b2, acc[1][2], 0, 0, 0);
    acc[1][3] = MFMA_BF16(a1, b3, acc[1][3], 0, 0, 0);
    acc[2][0] = MFMA_BF16(a2, b0, acc[2][0], 0, 0, 0);
    acc[2][1] = MFMA_BF16(a2, b1, acc[2][1], 0, 0, 0);
    acc[2][2] = MFMA_BF16(a2, b2, acc[2][2], 0, 0, 0);
    acc[2][3] = MFMA_BF16(a2, b3, acc[2][3], 0, 0, 0);
    acc[3][0] = MFMA_BF16(a3, b0, acc[3][0], 0, 0, 0);
    acc[3][1] = MFMA_BF16(a3, b1, acc[3][1], 0, 0, 0);
    acc[3][2] = MFMA_BF16(a3, b2, acc[3][2], 0, 0, 0);
    acc[3][3] = MFMA_BF16(a3, b3, acc[3][3], 0, 0, 0);
    __builtin_amdgcn_s_setprio(0);
    __builtin_amdgcn_s_barrier();
    __builtin_amdgcn_sched_barrier(0);
    // ---------- P3: kk=1 i4-7 ; stage A-band1(tt+1) ; counted boundary ----------
    a4 = LD8(Ac + rdA + 4096 + cz1);
    a5 = LD8(Ac + rdA + 5120 + cz1);
    a6 = LD8(Ac + rdA + 6144 + cz1);
    a7 = LD8(Ac + rdA + 7168 + cz1);
    if (pf) {
      gload_lds16(AbU + kpf + (size_t)(64 + w8) * K,  Aw + (64 + w8) * 64);
      gload_lds16(AbU + kpf + (size_t)(192 + w8) * K, Aw + (192 + w8) * 64);
    }
    __builtin_amdgcn_s_barrier();
    asm volatile("s_waitcnt lgkmcnt(0)" ::: "memory");
    __builtin_amdgcn_sched_barrier(0);
    __builtin_amdgcn_s_setprio(1);
    acc[4][0] = MFMA_BF16(a4, b0, acc[4][0], 0, 0, 0);
    acc[4][1] = MFMA_BF16(a4, b1, acc[4][1], 0, 0, 0);
    acc[4][2] = MFMA_BF16(a4, b2, acc[4][2], 0, 0, 0);
    acc[4][3] = MFMA_BF16(a4, b3, acc[4][3], 0, 0, 0);
    acc[5][0] = MFMA_BF16(a5, b0, acc[5][0], 0, 0, 0);
    acc[5][1] = MFMA_BF16(a5, b1, acc[5][1], 0, 0, 0);
    acc[5][2] = MFMA_BF16(a5, b2, acc[5][2], 0, 0, 0);
    acc[5][3] = MFMA_BF16(a5, b3, acc[5][3], 0, 0, 0);
    acc[6][0] = MFMA_BF16(a6, b0, acc[6][0], 0, 0, 0);
    acc[6][1] = MFMA_BF16(a6, b1, acc[6][1], 0, 0, 0);
    acc[6][2] = MFMA_BF16(a6, b2, acc[6][2], 0, 0, 0);
    acc[6][3] = MFMA_BF16(a6, b3, acc[6][3], 0, 0, 0);
    acc[7][0] = MFMA_BF16(a7, b0, acc[7][0], 0, 0, 0);
    acc[7][1] = MFMA_BF16(a7, b1, acc[7][1], 0, 0, 0);
    acc[7][2] = MFMA_BF16(a7, b2, acc[7][2], 0, 0, 0);
    acc[7][3] = MFMA_BF16(a7, b3, acc[7][3], 0, 0, 0);
    __builtin_amdgcn_s_setprio(0);
    if (pf) {
      asm volatile("s_waitcnt vmcnt(2)" ::: "memory");  // B-h0/h1 + A-band0 (tt+1) landed
      __builtin_amdgcn_s_barrier();
      __builtin_amdgcn_sched_barrier(0);
    }
  }
  // epilogue: C/D layout col=lane&15, row=quad*4+reg
  float bcol[4];
  #pragma unroll
  for (int j = 0; j < 4; j++) bcol[j] = bias[n0 + wn + j * 16 + l16];
  #pragma unroll
  for (int i = 0; i < 8; i++) {
    #pragma unroll
    for (int r = 0; r < 4; r++) {
      int row = m0 + wm + i * 16 + quad * 4 + r;
      #pragma unroll
      for (int j = 0; j < 4; j++) {
        int col = n0 + wn + j * 16 + l16;
        float v = acc[i][j][r] + bcol[j];
        if (ACT == 1) {
          float e = v * (2.3022082f + 0.1029431f * v * v);
          float tt2 = exp2f(fminf(e, 80.0f));
          v = v * tt2 / (tt2 + 1.0f);
        }
        if (RESID == 1) v += b2f(((const u16*)resid)[(size_t)row * N + col]);
        if (RESID == 2) v += ((const float*)resid)[(size_t)row * N + col];
        if (OUTF32) ((float*)Cv)[(size_t)row * ldc + col] = v;
        else        ((u16*)Cv)[(size_t)row * ldc + col] = f2b(v);
      }
    }
  }
}

// ======================= gemm256n_k: BM=256 BN=128, 3-buf, counted vmcnt (O-proj + FFN2) =======
// Measured r7: 808 TF (FFN2 K=4096), ~750 TF (O-proj). Exact 1-round grid at N=1024.
// NOT for wide-N K=1024 GEMMs (r8: FFN1 FETCH 74->140MB, 97.5->111us).
template<int ACT, int RESID, int OUTF32>
__global__ __launch_bounds__(512, 2) void gemm256n_k(const u16* __restrict__ A, const u16* __restrict__ Bt,
                                                     const float* __restrict__ bias, const void* __restrict__ resid,
                                                     void* __restrict__ Cv, int M, int N, int K, int ldc) {
  __shared__ u16 As[3][256 * 64];   // 3 x 32KB
  __shared__ u16 Bs[3][128 * 64];   // 3 x 16KB
  int Ny = N >> 7;
  int lin = blockIdx.y * 32 + blockIdx.x;
  int c8 = lin & 7, sblk = lin >> 3;
  int mq = sblk / Ny;
  int m0 = ((mq << 3) | c8) << 8;
  int n0 = (sblk - mq * Ny) << 7;
  int t = threadIdx.x;
  int wave = t >> 6, lane = t & 63, quad = lane >> 4, l16 = lane & 15;
  int wm = (wave >> 1) << 6;            // 0 | 64 | 128 | 192
  int wn = (wave & 1) << 6;             // 0 | 64
  f32x4 acc[4][4] = {};
  int lrow = lane >> 3;                        // 0..7
  int lchunk = (lane & 7) ^ lrow;              // src chunk = logical ^ (row&7)
  const u16* Ab = A + (size_t)(m0 + wave * 32 + lrow) * K + lchunk * 8;
  const u16* Bb = Bt + (size_t)(n0 + wave * 16 + lrow) * K + lchunk * 8;
  const int sbA = wave * 32 * 64;              // A staging slab (4 instrs x 8 rows)
  const int sbB = wave * 16 * 64;              // B staging slab (2 instrs x 8 rows)
  const int x7 = l16 & 7;
  const int rdA = (wm + l16) * 64;             // + i*1024 + cz
  const int rdB = (wn + l16) * 64;             // + j*1024 + cz
  const int cz0 = (quad ^ x7) * 8;
  const int cz1 = ((4 + quad) ^ x7) * 8;
  const int niter = K >> 6;
  // ---- prologue: stage tiles 0,1 (12 gloads/wave) ----
  #pragma unroll
  for (int p = 0; p < 2; p++) {
    #pragma unroll
    for (int g = 0; g < 4; g++)
      gload_lds16(Ab + (p << 6) + (size_t)g * 8 * K, &As[p][sbA + g * 8 * 64]);
    #pragma unroll
    for (int g = 0; g < 2; g++)
      gload_lds16(Bb + (p << 6) + (size_t)g * 8 * K, &Bs[p][sbB + g * 8 * 64]);
  }
  asm volatile("s_waitcnt vmcnt(6)" ::: "memory");   // tile0 landed; tile1 in flight
  __builtin_amdgcn_s_barrier();
  __builtin_amdgcn_sched_barrier(0);
  int cur = 0;
  for (int tt = 0; tt < niter; tt++) {
    int wb = cur + 2; if (wb >= 3) wb -= 3;
    const bool pf = (tt + 2 < niter);
    const int kpf = (tt + 2) << 6;
    const u16* Ac = &As[cur][0];
    const u16* Bc = &Bs[cur][0];
    short8 a0, a1, a2, a3, b0, b1, b2, b3;
    // ---------- P0: kk=0 (a0-3, b0-3) ; stage A(tile tt+2) ----------
    a0 = LD8(Ac + rdA + cz0);
    a1 = LD8(Ac + rdA + 1024 + cz0);
    a2 = LD8(Ac + rdA + 2048 + cz0);
    a3 = LD8(Ac + rdA + 3072 + cz0);
    b0 = LD8(Bc + rdB + cz0);
    b1 = LD8(Bc + rdB + 1024 + cz0);
    b2 = LD8(Bc + rdB + 2048 + cz0);
    b3 = LD8(Bc + rdB + 3072 + cz0);
    if (pf) {
      #pragma unroll
      for (int g = 0; g < 4; g++)
        gload_lds16(Ab + kpf + (size_t)g * 8 * K, &As[wb][sbA + g * 8 * 64]);
    }
    __builtin_amdgcn_s_barrier();
    asm volatile("s_waitcnt lgkmcnt(0)" ::: "memory");
    __builtin_amdgcn_sched_barrier(0);
    __builtin_amdgcn_s_setprio(1);
    acc[0][0] = MFMA_BF16(a0, b0, acc[0][0], 0, 0, 0);
    acc[0][1] = MFMA_BF16(a0, b1, acc[0][1], 0, 0, 0);
    acc[0][2] = MFMA_BF16(a0, b2, acc[0][2], 0, 0, 0);
    acc[0][3] = MFMA_BF16(a0, b3, acc[0][3], 0, 0, 0);
    acc[1][0] = MFMA_BF16(a1, b0, acc[1][0], 0, 0, 0);
    acc[1][1] = MFMA_BF16(a1, b1, acc[1][1], 0, 0, 0);
    acc[1][2] = MFMA_BF16(a1, b2, acc[1][2], 0, 0, 0);
    acc[1][3] = MFMA_BF16(a1, b3, acc[1][3], 0, 0, 0);
    acc[2][0] = MFMA_BF16(a2, b0, acc[2][0], 0, 0, 0);
    acc[2][1] = MFMA_BF16(a2, b1, acc[2][1], 0, 0, 0);
    acc[2][2] = MFMA_BF16(a2, b2, acc[2][2], 0, 0, 0);
    acc[2][3] = MFMA_BF16(a2, b3, acc[2][3], 0, 0, 0);
    acc[3][0] = MFMA_BF16(a3, b0, acc[3][0], 0, 0, 0);
    acc[3][1] = MFMA_BF16(a3, b1, acc[3][1], 0, 0, 0);
    acc[3][2] = MFMA_BF16(a3, b2, acc[3][2], 0, 0, 0);
    acc[3][3] = MFMA_BF16(a3, b3, acc[3][3], 0, 0, 0);
    __builtin_amdgcn_s_setprio(0);
    __builtin_amdgcn_s_barrier();
    __builtin_amdgcn_sched_barrier(0);
    // ---------- P1: kk=1 (a,b re-read) ; stage B(tile tt+2) ----------
    a0 = LD8(Ac + rdA + cz1);
    a1 = LD8(Ac + rdA + 1024 + cz1);
    a2 = LD8(Ac + rdA + 2048 + cz1);
    a3 = LD8(Ac + rdA + 3072 + cz1);
    b0 = LD8(Bc + rdB + cz1);
    b1 = LD8(Bc + rdB + 1024 + cz1);
    b2 = LD8(Bc + rdB + 2048 + cz1);
    b3 = LD8(Bc + rdB + 3072 + cz1);
    if (pf) {
      #pragma unroll
      for (int g = 0; g < 2; g++)
        gload_lds16(Bb + kpf + (size_t)g * 8 * K, &Bs[wb][sbB + g * 8 * 64]);
    }
    __builtin_amdgcn_s_barrier();
    asm volatile("s_waitcnt lgkmcnt(0)" ::: "memory");
    __builtin_amdgcn_sched_barrier(0);
    __builtin_amdgcn_s_setprio(1);
    acc[0][0] = MFMA_BF16(a0, b0, acc[0][0], 0, 0, 0);
    acc[0][1] = MFMA_BF16(a0, b1, acc[0][1], 0, 0, 0);
    acc[0][2] = MFMA_BF16(a0, b2, acc[0][2], 0, 0, 0);
    acc[0][3] = MFMA_BF16(a0, b3, acc[0][3], 0, 0, 0);
    acc[1][0] = MFMA_BF16(a1, b0, acc[1][0], 0, 0, 0);
    acc[1][1] = MFMA_BF16(a1, b1, acc[1][1], 0, 0, 0);
    acc[1][2] = MFMA_BF16(a1, b2, acc[1][2], 0, 0, 0);
    acc[1][3] = MFMA_BF16(a1, b3, acc[1][3], 0, 0, 0);
    acc[2][0] = MFMA_BF16(a2, b0, acc[2][0], 0, 0, 0);
    acc[2][1] = MFMA_BF16(a2, b1, acc[2][1], 0, 0, 0);
    acc[2][2] = MFMA_BF16(a2, b2, acc[2][2], 0, 0, 0);
    acc[2][3] = MFMA_BF16(a2, b3, acc[2][3], 0, 0, 0);
    acc[3][0] = MFMA_BF16(a3, b0, acc[3][0], 0, 0, 0);
    acc[3][1] = MFMA_BF16(a3, b1, acc[3][1], 0, 0, 0);
    acc[3][2] = MFMA_BF16(a3, b2, acc[3][2], 0, 0, 0);
    acc[3][3] = MFMA_BF16(a3, b3, acc[3][3], 0, 0, 0);
    __builtin_amdgcn_s_setprio(0);
    if (tt + 2 < niter) {
      asm volatile("s_waitcnt vmcnt(6)" ::: "memory");  // tile tt+1 landed; tt+2 in flight
    } else if (tt + 1 < niter) {
      asm volatile("s_waitcnt vmcnt(0)" ::: "memory");  // tail drain
    }
    if (tt + 1 < niter) {
      __builtin_amdgcn_s_barrier();
      __builtin_amdgcn_sched_barrier(0);
    }
    cur = (cur == 2) ? 0 : cur + 1;
  }
  // epilogue: C/D layout col=lane&15, row=quad*4+reg
  float bcol[4];
  #pragma unroll
  for (int j = 0; j < 4; j++) bcol[j] = bias[n0 + wn + j * 16 + l16];
  #pragma unroll
  for (int i = 0; i < 4; i++) {
    #pragma unroll
    for (int r = 0; r < 4; r++) {
      int row = m0 + wm + i * 16 + quad * 4 + r;
      #pragma unroll
      for (int j = 0; j < 4; j++) {
        int col = n0 + wn + j * 16 + l16;
        float v = acc[i][j][r] + bcol[j];
        if (ACT == 1) {
          float e = v * (2.3022082f + 0.1029431f * v * v);
          float tt2 = exp2f(fminf(e, 80.0f));
          v = v * tt2 / (tt2 + 1.0f);
        }
        if (RESID == 1) v += b2f(((const u16*)resid)[(size_t)row * N + col]);
        if (RESID == 2) v += ((const float*)resid)[(size_t)row * N + col];
        if (OUTF32) ((float*)Cv)[(size_t)row * ldc + col] = v;
        else        ((u16*)Cv)[(size_t)row * ldc + col] = f2b(v);
      }
    }
  }
}

// ---------------- Flash attention: grid (B*H, S/128); qkv strided (ld=3072) ----------------
// r10 structure (proven): 2-buffer __syncthreads skeleton, 8 waves/block covering 128 Q-rows
// (shared K/V tiles serve 2x Q rows; per-wave staging 2 gloads/iter), cvt_pk packed bf16.
__global__ __launch_bounds__(512) void attn_k(const u16* __restrict__ QKV, const u16* __restrict__ VT,
                                              u16* __restrict__ ctx) {
  int bh = blockIdx.x;
  int b = bh >> 4;
  int q0 = blockIdx.y * 128;
  int t = threadIdx.x, wave = t >> 6, lane = t & 63, quad = lane >> 4, l16 = lane & 15;
  __shared__ u16 Ks[2][64 * 64];    // [key][d], XOR-swizzled chunks
  __shared__ u16 Vs[2][64 * 64];    // [d][key-of-tile], XOR-swizzled
  __shared__ u16 Plds[8][16][72];   // per-wave P strip (wave-private)
  const size_t base = ((size_t)b * 1024) * 3072 + (size_t)(bh & 15) * 64;
  const u16* Kbase = QKV + base + 1024;
  const u16* vtb = VT + (size_t)bh * 64 * 1024;
  int lrow = lane >> 3;                  // 0..7
  int lchunk = (lane & 7) ^ lrow;        // source-permute => phys chunk = logical ^ (row&7)
  int srow = wave * 8;                   // this wave's 8-row staging slab of the 64-row tile
  short8 qa[2];  // Q A-frags: A[m=l16][k=quad*8+j], k-halves 0/32
  #pragma unroll
  for (int kh = 0; kh < 2; kh++)
    qa[kh] = *(const short8*)(QKV + base + (size_t)(q0 + wave * 16 + l16) * 3072 + kh * 32 + quad * 8);
  gload_lds16(Kbase + (size_t)(srow + lrow) * 3072 + lchunk * 8, &Ks[0][srow * 64]);
  gload_lds16(vtb + (size_t)(srow + lrow) * 1024 + lchunk * 8, &Vs[0][srow * 64]);
  f32x4 o[4] = {};
  float l_acc[4] = {0.f, 0.f, 0.f, 0.f};
  for (int c = 0; c < 16; c++) {
    int buf = c & 1;
    __syncthreads();  // drains tile-c DMA; fences buf^1 readers from iter c-1
    if (c < 15) {
      gload_lds16(Kbase + (size_t)((c + 1) * 64 + srow + lrow) * 3072 + lchunk * 8, &Ks[buf ^ 1][srow * 64]);
      gload_lds16(vtb + (size_t)(srow + lrow) * 1024 + (c + 1) * 64 + lchunk * 8, &Vs[buf ^ 1][srow * 64]);
    }
    f32x4 s[4] = {};
    #pragma unroll
    for (int kh = 0; kh < 2; kh++)
      #pragma unroll
      for (int j = 0; j < 4; j++) {
        int row = j * 16 + l16;
        int pc = (kh * 4 + quad) ^ (row & 7);
        short8 kb = *(const short8*)(&Ks[buf][row * 64 + pc * 8]);
        s[j] = MFMA_BF16(qa[kh], kb, s[j], 0, 0, 0);
      }
    #pragma unroll
    for (int j = 0; j < 4; j++)
      #pragma unroll
      for (int rp = 0; rp < 4; rp += 2) {
        float p0 = exp2f(s[j][rp]     * 0.18033688011112042f);  // 2^(s*log2e/8)
        float p1 = exp2f(s[j][rp + 1] * 0.18033688011112042f);
        l_acc[rp] += p0;
        l_acc[rp + 1] += p1;
        u32 pk;
        asm("v_cvt_pk_bf16_f32 %0, %1, %2" : "=v"(pk) : "v"(p0), "v"(p1));
        Plds[wave][quad * 4 + rp][j * 16 + l16]     = (u16)pk;
        Plds[wave][quad * 4 + rp + 1][j * 16 + l16] = (u16)(pk >> 16);
      }
    #pragma unroll
    for (int kh = 0; kh < 2; kh++) {
      short8 pa = *(const short8*)(&Plds[wave][l16][kh * 32 + quad * 8]);
      #pragma unroll
      for (int d4 = 0; d4 < 4; d4++) {
        int row = d4 * 16 + l16;
        int pc = (kh * 4 + quad) ^ (row & 7);
        short8 vb = *(const short8*)(&Vs[buf][row * 64 + pc * 8]);
        o[d4] = MFMA_BF16(pa, vb, o[d4], 0, 0, 0);
      }
    }
  }
  #pragma unroll
  for (int off = 1; off < 16; off <<= 1)
    #pragma unroll
    for (int r = 0; r < 4; r++) l_acc[r] += __shfl_xor(l_acc[r], off);
  #pragma unroll
  for (int r = 0; r < 4; r++) {
    float inv = 1.0f / l_acc[r];
    size_t row = (size_t)b * 1024 + q0 + wave * 16 + quad * 4 + r;
    #pragma unroll
    for (int d4 = 0; d4 < 4; d4++) {
      int col = (bh & 15) * 64 + d4 * 16 + l16;
      ctx[row * 1024 + col] = f2b(o[d4][r] * inv);
    }
  }
}

// ---------------- launch ----------------
extern "C" void kernel_launch(void* const* d_in, const int* in_sizes, int n_in,
                              void* d_out, int out_size, void* d_ws, size_t ws_size,
                              hipStream_t stream) {
  const float* x   = (const float*)d_in[0];
  const float* Wq  = (const float*)d_in[1];  const float* bq  = (const float*)d_in[2];
  const float* Wk  = (const float*)d_in[3];  const float* bk  = (const float*)d_in[4];
  const float* Wv  = (const float*)d_in[5];  const float* bv  = (const float*)d_in[6];
  const float* Wo  = (const float*)d_in[7];  const float* bo  = (const float*)d_in[8];
  const float* W1  = (const float*)d_in[9];  const float* b1  = (const float*)d_in[10];
  const float* W2  = (const float*)d_in[11]; const float* b2  = (const float*)d_in[12];
  const float* g1  = (const float*)d_in[13]; const float* be1 = (const float*)d_in[14];
  const float* g2  = (const float*)d_in[15]; const float* be2 = (const float*)d_in[16];

  char* ws = (char*)d_ws;
  const size_t MB = 1024 * 1024;
  u16* h1    = (u16*)(ws + 0 * MB);
  u16* qkv   = (u16*)(ws + 16 * MB);
  u16* x1    = (u16*)(ws + 16 * MB);
  u16* h2    = (u16*)(ws + 32 * MB);
  u16* W2T   = (u16*)(ws + 48 * MB);
  u16* WqkvT = (u16*)(ws + 64 * MB);
  u16* WoT   = (u16*)(ws + 70 * MB);
  u16* W1T   = (u16*)(ws + 72 * MB);
  float* bqkv = (float*)(ws + 80 * MB);
  u16* h3f   = (u16*)(ws + 80 * MB);
  u16* vt    = h1;
  u16* ctx   = (u16*)d_out;
  float* out = (float*)d_out;

  transpose_k<<<dim3(32, 32), 256, 0, stream>>>(Wq, WqkvT, 1024, 1024);
  transpose_k<<<dim3(32, 32), 256, 0, stream>>>(Wk, WqkvT + (size_t)1024 * 1024, 1024, 1024);
  transpose_k<<<dim3(32, 32), 256, 0, stream>>>(Wv, WqkvT + (size_t)2048 * 1024, 1024, 1024);
  transpose_k<<<dim3(32, 32), 256, 0, stream>>>(Wo, WoT, 1024, 1024);
  transpose_k<<<dim3(128, 32), 256, 0, stream>>>(W1, W1T, 1024, 4096);
  cat3_k<<<12, 256, 0, stream>>>(bq, bk, bv, bqkv);

  ln_k<1><<<8192, 256, 0, stream>>>(x, g1, be1, h1);

  gemm256_k<0, 0, 0><<<dim3(32, 12), 512, 0, stream>>>(h1, WqkvT, bqkv, nullptr, qkv,
                                                       8192, 3072, 1024, 3072);    // fused QKV

  vtrans_k<<<dim3(64, 128), 256, 0, stream>>>(qkv, vt);                            // vt = h1 (dead)

  attn_k<<<dim3(128, 8), 512, 0, stream>>>(qkv, vt, ctx);                          // ctx = d_out[0,16M)

  gemm256n_k<0, 2, 0><<<dim3(32, 8), 512, 0, stream>>>(ctx, WoT, bo, x, x1,
                                                       8192, 1024, 1024, 1024);    // x1 (+fp32 x)

  transpose_k<<<dim3(32, 128), 256, 0, stream>>>(W2, W2T, 4096, 1024);             // into dead v region

  ln_k<0><<<8192, 256, 0, stream>>>(x1, g2, be2, h2);

  gemm256_k<1, 0, 0><<<dim3(32, 16), 512, 0, stream>>>(h2, W1T, b1, nullptr, h3f,
                                                       8192, 4096, 1024, 4096);    // FFN1 + GELU
  gemm256n_k<0, 1, 1><<<dim3(32, 8), 512, 0, stream>>>(h3f, W2T, b2, x1, out,
                                                       8192, 1024, 4096, 1024);    // FFN2 + resid

  (void)in_sizes; (void)n_in; (void)out_size; (void)ws_size;
}

// Round 12
// 497.403 us; speedup vs baseline: 1.0165x; 1.0165x over previous
//
#include <hip/hip_runtime.h>
#include <hip/hip_bf16.h>
#include <math.h>
#include <stdint.h>

typedef unsigned short u16;
typedef unsigned int u32;
typedef __attribute__((ext_vector_type(8))) short short8;   // 8 bf16 = 4 VGPRs (MFMA A/B frag)
typedef __attribute__((ext_vector_type(4))) float f32x4;    // MFMA C/D frag

__device__ __forceinline__ float b2f(u16 u) {
  union { u32 i; float f; } v; v.i = ((u32)u) << 16; return v.f;
}
__device__ __forceinline__ u16 f2b(float f) {
  union { float f; u32 i; } v; v.f = f;
  return (u16)((v.i + 0x7FFFu + ((v.i >> 16) & 1u)) >> 16);  // RNE
}

// async global->LDS DMA, 16B per lane; LDS dest = wave-uniform base + lane*16B
__device__ __forceinline__ void gload_lds16(const u16* g, u16* l) {
  __builtin_amdgcn_global_load_lds((const __attribute__((address_space(1))) void*)g,
                                   (__attribute__((address_space(3))) void*)l, 16, 0, 0);
}

#define LD8(p) (*(const short8*)(p))
#define MFMA_BF16 __builtin_amdgcn_mfma_f32_16x16x32_bf16

// ---------------- fused transpose+convert: fp32 (K x N) -> bf16 (N x K) ----------------
__global__ __launch_bounds__(256) void transpose_k(const float* __restrict__ in,
                                                   u16* __restrict__ out, int K, int N) {
  __shared__ u16 tile[32][33];
  int n0 = blockIdx.x * 32, k0 = blockIdx.y * 32;
  int tx = threadIdx.x & 31, ty = threadIdx.x >> 5;
  #pragma unroll
  for (int i = ty; i < 32; i += 8)
    tile[i][tx] = f2b(in[(size_t)(k0 + i) * N + n0 + tx]);
  __syncthreads();
  #pragma unroll
  for (int i = ty; i < 32; i += 8)
    out[(size_t)(n0 + i) * K + k0 + tx] = tile[tx][i];
}

// ---------------- concat 3 x 1024 fp32 biases ----------------
__global__ __launch_bounds__(256) void cat3_k(const float* __restrict__ a, const float* __restrict__ b,
                                              const float* __restrict__ c, float* __restrict__ o) {
  int i = blockIdx.x * 256 + threadIdx.x;
  o[i] = i < 1024 ? a[i] : (i < 2048 ? b[i - 1024] : c[i - 2048]);
}

// ---------------- per-head V transpose from strided qkv: v[s][2048+h*64+d] -> vt[(bh*64+d)][s] ----------------
__global__ __launch_bounds__(256) void vtrans_k(const u16* __restrict__ qkv, u16* __restrict__ vt) {
  __shared__ u16 tile[32][33];
  int bh = blockIdx.y, b = bh >> 4, h = bh & 15;
  int s0 = (blockIdx.x & 31) * 32, d0 = (blockIdx.x >> 5) * 32;
  int tx = threadIdx.x & 31, ty = threadIdx.x >> 5;
  #pragma unroll
  for (int i = ty; i < 32; i += 8)
    tile[i][tx] = qkv[(size_t)(b * 1024 + s0 + i) * 3072 + 2048 + h * 64 + d0 + tx];
  __syncthreads();
  #pragma unroll
  for (int i = ty; i < 32; i += 8)
    vt[(size_t)(bh * 64 + d0 + i) * 1024 + s0 + tx] = tile[tx][i];
}

// ---------------- LayerNorm over D=1024, one block per row; FP32IN: x fp32 vs bf16 ----------------
template<int FP32IN>
__global__ __launch_bounds__(256) void ln_k(const void* __restrict__ xv, const float* __restrict__ g,
                                            const float* __restrict__ be, u16* __restrict__ out) {
  int row = blockIdx.x, t = threadIdx.x;
  float f0, f1, f2, f3;
  if (FP32IN) {
    const float* xr = (const float*)xv + (size_t)row * 1024;
    float4 x4 = *(const float4*)(xr + t * 4);
    f0 = x4.x; f1 = x4.y; f2 = x4.z; f3 = x4.w;
  } else {
    const u16* xr = (const u16*)xv + (size_t)row * 1024;
    ushort4 x4 = *(const ushort4*)(xr + t * 4);
    f0 = b2f(x4.x); f1 = b2f(x4.y); f2 = b2f(x4.z); f3 = b2f(x4.w);
  }
  float s = f0 + f1 + f2 + f3;
  float ss = f0 * f0 + f1 * f1 + f2 * f2 + f3 * f3;
  #pragma unroll
  for (int off = 32; off > 0; off >>= 1) { s += __shfl_down(s, off); ss += __shfl_down(ss, off); }
  __shared__ float sb[4], ssb[4];
  if ((t & 63) == 0) { sb[t >> 6] = s; ssb[t >> 6] = ss; }
  __syncthreads();
  s = sb[0] + sb[1] + sb[2] + sb[3];
  ss = ssb[0] + ssb[1] + ssb[2] + ssb[3];
  float mu = s * (1.0f / 1024.0f);
  float var = ss * (1.0f / 1024.0f) - mu * mu;
  float rstd = rsqrtf(var + 1e-5f);
  float4 gv = *(const float4*)(g + t * 4);
  float4 bv = *(const float4*)(be + t * 4);
  ushort4 o;
  o.x = f2b((f0 - mu) * rstd * gv.x + bv.x);
  o.y = f2b((f1 - mu) * rstd * gv.y + bv.y);
  o.z = f2b((f2 - mu) * rstd * gv.z + bv.z);
  o.w = f2b((f3 - mu) * rstd * gv.w + bv.w);
  *(ushort4*)(out + (size_t)row * 1024 + t * 4) = o;
}

// ======================= gemm256_k: BK=64 4-phase schedule (FFN1) ==============================
// r10-proven version (r11's half-tile counted-vmcnt variant regressed: the boundary vmcnt(0)
// waits on loads issued >=2 phases (~800cy) earlier, which have already landed -- it was never
// the stall). BM=BN=256 (traffic-minimal for K=1024 wide-N), 8 waves (2M x 4N), per-wave 128x64
// (acc[8][4]), 2 LDS buffers (128KB). P0/P1 stage A/B of tile tt+1; P2/P3 pure compute.
// Swizzle: 128B row pitch, chunk XOR (row&7) (0 conflicts measured).
template<int ACT, int RESID, int OUTF32>
__global__ __launch_bounds__(512, 2) void gemm256_k(const u16* __restrict__ A, const u16* __restrict__ Bt,
                                                    const float* __restrict__ bias, const void* __restrict__ resid,
                                                    void* __restrict__ Cv, int M, int N, int K, int ldc) {
  __shared__ u16 As[2][256 * 64];   // 2 x 32KB
  __shared__ u16 Bs[2][256 * 64];   // 2 x 32KB
  int Ny = N >> 8;
  int lin = blockIdx.y * 32 + blockIdx.x;
  int c8 = lin & 7, sblk = lin >> 3;
  int mq = sblk / Ny;
  int m0 = ((mq << 3) | c8) << 8;
  int n0 = (sblk - mq * Ny) << 8;
  int t = threadIdx.x;
  int wave = t >> 6, lane = t & 63, quad = lane >> 4, l16 = lane & 15;
  int wm = (wave >> 2) << 7;            // 0 | 128
  int wn = (wave & 3) << 6;             // 0..192
  f32x4 acc[8][4] = {};
  int lrow = lane >> 3;                        // 0..7
  int lchunk = (lane & 7) ^ lrow;              // src chunk = logical ^ (row&7)
  const u16* Ab = A + (size_t)(m0 + wave * 32 + lrow) * K + lchunk * 8;
  const u16* Bb = Bt + (size_t)(n0 + wave * 32 + lrow) * K + lchunk * 8;
  const int sbase = wave * 32 * 64;            // wave's staging slab base (elements); +g*8*64
  const int x7 = l16 & 7;
  const int rdA = (wm + l16) * 64;             // + i*1024 + cswz
  const int rdB = (wn + l16) * 64;             // + j*1024 + cswz
  const int cz0 = (quad ^ x7) * 8;             // kk=0: logical chunk = quad
  const int cz1 = ((4 + quad) ^ x7) * 8;       // kk=1: logical chunk = 4+quad
  const int niter = K >> 6;
  // ---- prologue: stage tile 0 into buf0 (8 gloads/wave) ----
  #pragma unroll
  for (int g = 0; g < 4; g++) {
    gload_lds16(Ab + (size_t)g * 8 * K, &As[0][sbase + g * 8 * 64]);
    gload_lds16(Bb + (size_t)g * 8 * K, &Bs[0][sbase + g * 8 * 64]);
  }
  asm volatile("s_waitcnt vmcnt(0)" ::: "memory");
  __builtin_amdgcn_s_barrier();
  __builtin_amdgcn_sched_barrier(0);
  for (int tt = 0; tt < niter; tt++) {
    int buf = tt & 1;
    const bool pf = (tt + 1 < niter);
    const int kpf = (tt + 1) << 6;
    const u16* Ac = &As[buf][0];
    const u16* Bc = &Bs[buf][0];
    u16* Aw = &As[buf ^ 1][0];
    u16* Bw = &Bs[buf ^ 1][0];
    short8 a0, a1, a2, a3, a4, a5, a6, a7, b0, b1, b2, b3;
    // ---------- P0: kk=0 i0-3 + all b ; stage A(tile tt+1) ----------
    a0 = LD8(Ac + rdA + cz0);
    a1 = LD8(Ac + rdA + 1024 + cz0);
    a2 = LD8(Ac + rdA + 2048 + cz0);
    a3 = LD8(Ac + rdA + 3072 + cz0);
    b0 = LD8(Bc + rdB + cz0);
    b1 = LD8(Bc + rdB + 1024 + cz0);
    b2 = LD8(Bc + rdB + 2048 + cz0);
    b3 = LD8(Bc + rdB + 3072 + cz0);
    if (pf) {
      #pragma unroll
      for (int g = 0; g < 4; g++)
        gload_lds16(Ab + kpf + (size_t)g * 8 * K, Aw + sbase + g * 8 * 64);
    }
    __builtin_amdgcn_s_barrier();
    asm volatile("s_waitcnt lgkmcnt(0)" ::: "memory");
    __builtin_amdgcn_sched_barrier(0);
    __builtin_amdgcn_s_setprio(1);
    acc[0][0] = MFMA_BF16(a0, b0, acc[0][0], 0, 0, 0);
    acc[0][1] = MFMA_BF16(a0, b1, acc[0][1], 0, 0, 0);
    acc[0][2] = MFMA_BF16(a0, b2, acc[0][2], 0, 0, 0);
    acc[0][3] = MFMA_BF16(a0, b3, acc[0][3], 0, 0, 0);
    acc[1][0] = MFMA_BF16(a1, b0, acc[1][0], 0, 0, 0);
    acc[1][1] = MFMA_BF16(a1, b1, acc[1][1], 0, 0, 0);
    acc[1][2] = MFMA_BF16(a1, b2, acc[1][2], 0, 0, 0);
    acc[1][3] = MFMA_BF16(a1, b3, acc[1][3], 0, 0, 0);
    acc[2][0] = MFMA_BF16(a2, b0, acc[2][0], 0, 0, 0);
    acc[2][1] = MFMA_BF16(a2, b1, acc[2][1], 0, 0, 0);
    acc[2][2] = MFMA_BF16(a2, b2, acc[2][2], 0, 0, 0);
    acc[2][3] = MFMA_BF16(a2, b3, acc[2][3], 0, 0, 0);
    acc[3][0] = MFMA_BF16(a3, b0, acc[3][0], 0, 0, 0);
    acc[3][1] = MFMA_BF16(a3, b1, acc[3][1], 0, 0, 0);
    acc[3][2] = MFMA_BF16(a3, b2, acc[3][2], 0, 0, 0);
    acc[3][3] = MFMA_BF16(a3, b3, acc[3][3], 0, 0, 0);
    __builtin_amdgcn_s_setprio(0);
    __builtin_amdgcn_s_barrier();
    __builtin_amdgcn_sched_barrier(0);
    // ---------- P1: kk=0 i4-7 ; stage B(tile tt+1) ----------
    a4 = LD8(Ac + rdA + 4096 + cz0);
    a5 = LD8(Ac + rdA + 5120 + cz0);
    a6 = LD8(Ac + rdA + 6144 + cz0);
    a7 = LD8(Ac + rdA + 7168 + cz0);
    if (pf) {
      #pragma unroll
      for (int g = 0; g < 4; g++)
        gload_lds16(Bb + kpf + (size_t)g * 8 * K, Bw + sbase + g * 8 * 64);
    }
    __builtin_amdgcn_s_barrier();
    asm volatile("s_waitcnt lgkmcnt(0)" ::: "memory");
    __builtin_amdgcn_sched_barrier(0);
    __builtin_amdgcn_s_setprio(1);
    acc[4][0] = MFMA_BF16(a4, b0, acc[4][0], 0, 0, 0);
    acc[4][1] = MFMA_BF16(a4, b1, acc[4][1], 0, 0, 0);
    acc[4][2] = MFMA_BF16(a4, b2, acc[4][2], 0, 0, 0);
    acc[4][3] = MFMA_BF16(a4, b3, acc[4][3], 0, 0, 0);
    acc[5][0] = MFMA_BF16(a5, b0, acc[5][0], 0, 0, 0);
    acc[5][1] = MFMA_BF16(a5, b1, acc[5][1], 0, 0, 0);
    acc[5][2] = MFMA_BF16(a5, b2, acc[5][2], 0, 0, 0);
    acc[5][3] = MFMA_BF16(a5, b3, acc[5][3], 0, 0, 0);
    acc[6][0] = MFMA_BF16(a6, b0, acc[6][0], 0, 0, 0);
    acc[6][1] = MFMA_BF16(a6, b1, acc[6][1], 0, 0, 0);
    acc[6][2] = MFMA_BF16(a6, b2, acc[6][2], 0, 0, 0);
    acc[6][3] = MFMA_BF16(a6, b3, acc[6][3], 0, 0, 0);
    acc[7][0] = MFMA_BF16(a7, b0, acc[7][0], 0, 0, 0);
    acc[7][1] = MFMA_BF16(a7, b1, acc[7][1], 0, 0, 0);
    acc[7][2] = MFMA_BF16(a7, b2, acc[7][2], 0, 0, 0);
    acc[7][3] = MFMA_BF16(a7, b3, acc[7][3], 0, 0, 0);
    __builtin_amdgcn_s_setprio(0);
    __builtin_amdgcn_s_barrier();
    __builtin_amdgcn_sched_barrier(0);
    // ---------- P2: kk=1 i0-3 + all b ----------
    a0 = LD8(Ac + rdA + cz1);
    a1 = LD8(Ac + rdA + 1024 + cz1);
    a2 = LD8(Ac + rdA + 2048 + cz1);
    a3 = LD8(Ac + rdA + 3072 + cz1);
    b0 = LD8(Bc + rdB + cz1);
    b1 = LD8(Bc + rdB + 1024 + cz1);
    b2 = LD8(Bc + rdB + 2048 + cz1);
    b3 = LD8(Bc + rdB + 3072 + cz1);
    __builtin_amdgcn_s_barrier();
    asm volatile("s_waitcnt lgkmcnt(0)" ::: "memory");
    __builtin_amdgcn_sched_barrier(0);
    __builtin_amdgcn_s_setprio(1);
    acc[0][0] = MFMA_BF16(a0, b0, acc[0][0], 0, 0, 0);
    acc[0][1] = MFMA_BF16(a0, b1, acc[0][1], 0, 0, 0);
    acc[0][2] = MFMA_BF16(a0, b2, acc[0][2], 0, 0, 0);
    acc[0][3] = MFMA_BF16(a0, b3, acc[0][3], 0, 0, 0);
    acc[1][0] = MFMA_BF16(a1, b0, acc[1][0], 0, 0, 0);
    acc[1][1] = MFMA_BF16(a1, b1, acc[1][1], 0, 0, 0);
    acc[1][2] = MFMA_BF16(a1, b2, acc[1][2], 0, 0, 0);
    acc[1][3] = MFMA_BF16(a1, b3, acc[1][3], 0, 0, 0);
    acc[2][0] = MFMA_BF16(a2, b0, acc[2][0], 0, 0, 0);
    acc[2][1] = MFMA_BF16(a2, b1, acc[2][1], 0, 0, 0);
    acc[2][2] = MFMA_BF16(a2, b2, acc[2][2], 0, 0, 0);
    acc[2][3] = MFMA_BF16(a2, b3, acc[2][3], 0, 0, 0);
    acc[3][0] = MFMA_BF16(a3, b0, acc[3][0], 0, 0, 0);
    acc[3][1] = MFMA_BF16(a3, b1, acc[3][1], 0, 0, 0);
    acc[3][2] = MFMA_BF16(a3, b2, acc[3][2], 0, 0, 0);
    acc[3][3] = MFMA_BF16(a3, b3, acc[3][3], 0, 0, 0);
    __builtin_amdgcn_s_setprio(0);
    __builtin_amdgcn_s_barrier();
    __builtin_amdgcn_sched_barrier(0);
    // ---------- P3: kk=1 i4-7 ; K-tile boundary ----------
    a4 = LD8(Ac + rdA + 4096 + cz1);
    a5 = LD8(Ac + rdA + 5120 + cz1);
    a6 = LD8(Ac + rdA + 6144 + cz1);
    a7 = LD8(Ac + rdA + 7168 + cz1);
    __builtin_amdgcn_s_barrier();
    asm volatile("s_waitcnt lgkmcnt(0)" ::: "memory");
    __builtin_amdgcn_sched_barrier(0);
    __builtin_amdgcn_s_setprio(1);
    acc[4][0] = MFMA_BF16(a4, b0, acc[4][0], 0, 0, 0);
    acc[4][1] = MFMA_BF16(a4, b1, acc[4][1], 0, 0, 0);
    acc[4][2] = MFMA_BF16(a4, b2, acc[4][2], 0, 0, 0);
    acc[4][3] = MFMA_BF16(a4, b3, acc[4][3], 0, 0, 0);
    acc[5][0] = MFMA_BF16(a5, b0, acc[5][0], 0, 0, 0);
    acc[5][1] = MFMA_BF16(a5, b1, acc[5][1], 0, 0, 0);
    acc[5][2] = MFMA_BF16(a5, b2, acc[5][2], 0, 0, 0);
    acc[5][3] = MFMA_BF16(a5, b3, acc[5][3], 0, 0, 0);
    acc[6][0] = MFMA_BF16(a6, b0, acc[6][0], 0, 0, 0);
    acc[6][1] = MFMA_BF16(a6, b1, acc[6][1], 0, 0, 0);
    acc[6][2] = MFMA_BF16(a6, b2, acc[6][2], 0, 0, 0);
    acc[6][3] = MFMA_BF16(a6, b3, acc[6][3], 0, 0, 0);
    acc[7][0] = MFMA_BF16(a7, b0, acc[7][0], 0, 0, 0);
    acc[7][1] = MFMA_BF16(a7, b1, acc[7][1], 0, 0, 0);
    acc[7][2] = MFMA_BF16(a7, b2, acc[7][2], 0, 0, 0);
    acc[7][3] = MFMA_BF16(a7, b3, acc[7][3], 0, 0, 0);
    __builtin_amdgcn_s_setprio(0);
    if (pf) {
      asm volatile("s_waitcnt vmcnt(0)" ::: "memory");  // loads issued >=2 phases ago
      __builtin_amdgcn_s_barrier();
      __builtin_amdgcn_sched_barrier(0);
    }
  }
  // epilogue: C/D layout col=lane&15, row=quad*4+reg
  float bcol[4];
  #pragma unroll
  for (int j = 0; j < 4; j++) bcol[j] = bias[n0 + wn + j * 16 + l16];
  #pragma unroll
  for (int i = 0; i < 8; i++) {
    #pragma unroll
    for (int r = 0; r < 4; r++) {
      int row = m0 + wm + i * 16 + quad * 4 + r;
      #pragma unroll
      for (int j = 0; j < 4; j++) {
        int col = n0 + wn + j * 16 + l16;
        float v = acc[i][j][r] + bcol[j];
        if (ACT == 1) {
          float e = v * (2.3022082f + 0.1029431f * v * v);
          float tt2 = exp2f(fminf(e, 80.0f));
          v = v * tt2 / (tt2 + 1.0f);
        }
        if (RESID == 1) v += b2f(((const u16*)resid)[(size_t)row * N + col]);
        if (RESID == 2) v += ((const float*)resid)[(size_t)row * N + col];
        if (OUTF32) ((float*)Cv)[(size_t)row * ldc + col] = v;
        else        ((u16*)Cv)[(size_t)row * ldc + col] = f2b(v);
      }
    }
  }
}

// ======================= gemm256n_k: BM=256 BN=128, 3-buf, counted vmcnt =======================
// (QKV + O-proj + FFN2.) Measured r7: 808 TF (FFN2 K=4096), ~750 TF (O-proj). Exact-round
// grids: N=1024 -> 256 blocks = 1/CU; N=3072 -> 768 = 3/CU (kills QKV's 1.5-round tail; r8
// decomposition: QKV on this kernel was -3.4us even in that regressing round).
template<int ACT, int RESID, int OUTF32>
__global__ __launch_bounds__(512, 2) void gemm256n_k(const u16* __restrict__ A, const u16* __restrict__ Bt,
                                                     const float* __restrict__ bias, const void* __restrict__ resid,
                                                     void* __restrict__ Cv, int M, int N, int K, int ldc) {
  __shared__ u16 As[3][256 * 64];   // 3 x 32KB
  __shared__ u16 Bs[3][128 * 64];   // 3 x 16KB
  int Ny = N >> 7;
  int lin = blockIdx.y * 32 + blockIdx.x;
  int c8 = lin & 7, sblk = lin >> 3;
  int mq = sblk / Ny;
  int m0 = ((mq << 3) | c8) << 8;
  int n0 = (sblk - mq * Ny) << 7;
  int t = threadIdx.x;
  int wave = t >> 6, lane = t & 63, quad = lane >> 4, l16 = lane & 15;
  int wm = (wave >> 1) << 6;            // 0 | 64 | 128 | 192
  int wn = (wave & 1) << 6;             // 0 | 64
  f32x4 acc[4][4] = {};
  int lrow = lane >> 3;                        // 0..7
  int lchunk = (lane & 7) ^ lrow;              // src chunk = logical ^ (row&7)
  const u16* Ab = A + (size_t)(m0 + wave * 32 + lrow) * K + lchunk * 8;
  const u16* Bb = Bt + (size_t)(n0 + wave * 16 + lrow) * K + lchunk * 8;
  const int sbA = wave * 32 * 64;              // A staging slab (4 instrs x 8 rows)
  const int sbB = wave * 16 * 64;              // B staging slab (2 instrs x 8 rows)
  const int x7 = l16 & 7;
  const int rdA = (wm + l16) * 64;             // + i*1024 + cz
  const int rdB = (wn + l16) * 64;             // + j*1024 + cz
  const int cz0 = (quad ^ x7) * 8;
  const int cz1 = ((4 + quad) ^ x7) * 8;
  const int niter = K >> 6;
  // ---- prologue: stage tiles 0,1 (12 gloads/wave) ----
  #pragma unroll
  for (int p = 0; p < 2; p++) {
    #pragma unroll
    for (int g = 0; g < 4; g++)
      gload_lds16(Ab + (p << 6) + (size_t)g * 8 * K, &As[p][sbA + g * 8 * 64]);
    #pragma unroll
    for (int g = 0; g < 2; g++)
      gload_lds16(Bb + (p << 6) + (size_t)g * 8 * K, &Bs[p][sbB + g * 8 * 64]);
  }
  asm volatile("s_waitcnt vmcnt(6)" ::: "memory");   // tile0 landed; tile1 in flight
  __builtin_amdgcn_s_barrier();
  __builtin_amdgcn_sched_barrier(0);
  int cur = 0;
  for (int tt = 0; tt < niter; tt++) {
    int wb = cur + 2; if (wb >= 3) wb -= 3;
    const bool pf = (tt + 2 < niter);
    const int kpf = (tt + 2) << 6;
    const u16* Ac = &As[cur][0];
    const u16* Bc = &Bs[cur][0];
    short8 a0, a1, a2, a3, b0, b1, b2, b3;
    // ---------- P0: kk=0 (a0-3, b0-3) ; stage A(tile tt+2) ----------
    a0 = LD8(Ac + rdA + cz0);
    a1 = LD8(Ac + rdA + 1024 + cz0);
    a2 = LD8(Ac + rdA + 2048 + cz0);
    a3 = LD8(Ac + rdA + 3072 + cz0);
    b0 = LD8(Bc + rdB + cz0);
    b1 = LD8(Bc + rdB + 1024 + cz0);
    b2 = LD8(Bc + rdB + 2048 + cz0);
    b3 = LD8(Bc + rdB + 3072 + cz0);
    if (pf) {
      #pragma unroll
      for (int g = 0; g < 4; g++)
        gload_lds16(Ab + kpf + (size_t)g * 8 * K, &As[wb][sbA + g * 8 * 64]);
    }
    __builtin_amdgcn_s_barrier();
    asm volatile("s_waitcnt lgkmcnt(0)" ::: "memory");
    __builtin_amdgcn_sched_barrier(0);
    __builtin_amdgcn_s_setprio(1);
    acc[0][0] = MFMA_BF16(a0, b0, acc[0][0], 0, 0, 0);
    acc[0][1] = MFMA_BF16(a0, b1, acc[0][1], 0, 0, 0);
    acc[0][2] = MFMA_BF16(a0, b2, acc[0][2], 0, 0, 0);
    acc[0][3] = MFMA_BF16(a0, b3, acc[0][3], 0, 0, 0);
    acc[1][0] = MFMA_BF16(a1, b0, acc[1][0], 0, 0, 0);
    acc[1][1] = MFMA_BF16(a1, b1, acc[1][1], 0, 0, 0);
    acc[1][2] = MFMA_BF16(a1, b2, acc[1][2], 0, 0, 0);
    acc[1][3] = MFMA_BF16(a1, b3, acc[1][3], 0, 0, 0);
    acc[2][0] = MFMA_BF16(a2, b0, acc[2][0], 0, 0, 0);
    acc[2][1] = MFMA_BF16(a2, b1, acc[2][1], 0, 0, 0);
    acc[2][2] = MFMA_BF16(a2, b2, acc[2][2], 0, 0, 0);
    acc[2][3] = MFMA_BF16(a2, b3, acc[2][3], 0, 0, 0);
    acc[3][0] = MFMA_BF16(a3, b0, acc[3][0], 0, 0, 0);
    acc[3][1] = MFMA_BF16(a3, b1, acc[3][1], 0, 0, 0);
    acc[3][2] = MFMA_BF16(a3, b2, acc[3][2], 0, 0, 0);
    acc[3][3] = MFMA_BF16(a3, b3, acc[3][3], 0, 0, 0);
    __builtin_amdgcn_s_setprio(0);
    __builtin_amdgcn_s_barrier();
    __builtin_amdgcn_sched_barrier(0);
    // ---------- P1: kk=1 (a,b re-read) ; stage B(tile tt+2) ----------
    a0 = LD8(Ac + rdA + cz1);
    a1 = LD8(Ac + rdA + 1024 + cz1);
    a2 = LD8(Ac + rdA + 2048 + cz1);
    a3 = LD8(Ac + rdA + 3072 + cz1);
    b0 = LD8(Bc + rdB + cz1);
    b1 = LD8(Bc + rdB + 1024 + cz1);
    b2 = LD8(Bc + rdB + 2048 + cz1);
    b3 = LD8(Bc + rdB + 3072 + cz1);
    if (pf) {
      #pragma unroll
      for (int g = 0; g < 2; g++)
        gload_lds16(Bb + kpf + (size_t)g * 8 * K, &Bs[wb][sbB + g * 8 * 64]);
    }
    __builtin_amdgcn_s_barrier();
    asm volatile("s_waitcnt lgkmcnt(0)" ::: "memory");
    __builtin_amdgcn_sched_barrier(0);
    __builtin_amdgcn_s_setprio(1);
    acc[0][0] = MFMA_BF16(a0, b0, acc[0][0], 0, 0, 0);
    acc[0][1] = MFMA_BF16(a0, b1, acc[0][1], 0, 0, 0);
    acc[0][2] = MFMA_BF16(a0, b2, acc[0][2], 0, 0, 0);
    acc[0][3] = MFMA_BF16(a0, b3, acc[0][3], 0, 0, 0);
    acc[1][0] = MFMA_BF16(a1, b0, acc[1][0], 0, 0, 0);
    acc[1][1] = MFMA_BF16(a1, b1, acc[1][1], 0, 0, 0);
    acc[1][2] = MFMA_BF16(a1, b2, acc[1][2], 0, 0, 0);
    acc[1][3] = MFMA_BF16(a1, b3, acc[1][3], 0, 0, 0);
    acc[2][0] = MFMA_BF16(a2, b0, acc[2][0], 0, 0, 0);
    acc[2][1] = MFMA_BF16(a2, b1, acc[2][1], 0, 0, 0);
    acc[2][2] = MFMA_BF16(a2, b2, acc[2][2], 0, 0, 0);
    acc[2][3] = MFMA_BF16(a2, b3, acc[2][3], 0, 0, 0);
    acc[3][0] = MFMA_BF16(a3, b0, acc[3][0], 0, 0, 0);
    acc[3][1] = MFMA_BF16(a3, b1, acc[3][1], 0, 0, 0);
    acc[3][2] = MFMA_BF16(a3, b2, acc[3][2], 0, 0, 0);
    acc[3][3] = MFMA_BF16(a3, b3, acc[3][3], 0, 0, 0);
    __builtin_amdgcn_s_setprio(0);
    if (tt + 2 < niter) {
      asm volatile("s_waitcnt vmcnt(6)" ::: "memory");  // tile tt+1 landed; tt+2 in flight
    } else if (tt + 1 < niter) {
      asm volatile("s_waitcnt vmcnt(0)" ::: "memory");  // tail drain
    }
    if (tt + 1 < niter) {
      __builtin_amdgcn_s_barrier();
      __builtin_amdgcn_sched_barrier(0);
    }
    cur = (cur == 2) ? 0 : cur + 1;
  }
  // epilogue: C/D layout col=lane&15, row=quad*4+reg
  float bcol[4];
  #pragma unroll
  for (int j = 0; j < 4; j++) bcol[j] = bias[n0 + wn + j * 16 + l16];
  #pragma unroll
  for (int i = 0; i < 4; i++) {
    #pragma unroll
    for (int r = 0; r < 4; r++) {
      int row = m0 + wm + i * 16 + quad * 4 + r;
      #pragma unroll
      for (int j = 0; j < 4; j++) {
        int col = n0 + wn + j * 16 + l16;
        float v = acc[i][j][r] + bcol[j];
        if (ACT == 1) {
          float e = v * (2.3022082f + 0.1029431f * v * v);
          float tt2 = exp2f(fminf(e, 80.0f));
          v = v * tt2 / (tt2 + 1.0f);
        }
        if (RESID == 1) v += b2f(((const u16*)resid)[(size_t)row * N + col]);
        if (RESID == 2) v += ((const float*)resid)[(size_t)row * N + col];
        if (OUTF32) ((float*)Cv)[(size_t)row * ldc + col] = v;
        else        ((u16*)Cv)[(size_t)row * ldc + col] = f2b(v);
      }
    }
  }
}

// ---------------- Flash attention: grid (B*H, S/128); qkv strided (ld=3072) ----------------
// r10 structure (proven): 2-buffer __syncthreads skeleton, 8 waves/block covering 128 Q-rows
// (shared K/V tiles serve 2x Q rows; per-wave staging 2 gloads/iter), cvt_pk packed bf16.
__global__ __launch_bounds__(512) void attn_k(const u16* __restrict__ QKV, const u16* __restrict__ VT,
                                              u16* __restrict__ ctx) {
  int bh = blockIdx.x;
  int b = bh >> 4;
  int q0 = blockIdx.y * 128;
  int t = threadIdx.x, wave = t >> 6, lane = t & 63, quad = lane >> 4, l16 = lane & 15;
  __shared__ u16 Ks[2][64 * 64];    // [key][d], XOR-swizzled chunks
  __shared__ u16 Vs[2][64 * 64];    // [d][key-of-tile], XOR-swizzled
  __shared__ u16 Plds[8][16][72];   // per-wave P strip (wave-private)
  const size_t base = ((size_t)b * 1024) * 3072 + (size_t)(bh & 15) * 64;
  const u16* Kbase = QKV + base + 1024;
  const u16* vtb = VT + (size_t)bh * 64 * 1024;
  int lrow = lane >> 3;                  // 0..7
  int lchunk = (lane & 7) ^ lrow;        // source-permute => phys chunk = logical ^ (row&7)
  int srow = wave * 8;                   // this wave's 8-row staging slab of the 64-row tile
  short8 qa[2];  // Q A-frags: A[m=l16][k=quad*8+j], k-halves 0/32
  #pragma unroll
  for (int kh = 0; kh < 2; kh++)
    qa[kh] = *(const short8*)(QKV + base + (size_t)(q0 + wave * 16 + l16) * 3072 + kh * 32 + quad * 8);
  gload_lds16(Kbase + (size_t)(srow + lrow) * 3072 + lchunk * 8, &Ks[0][srow * 64]);
  gload_lds16(vtb + (size_t)(srow + lrow) * 1024 + lchunk * 8, &Vs[0][srow * 64]);
  f32x4 o[4] = {};
  float l_acc[4] = {0.f, 0.f, 0.f, 0.f};
  for (int c = 0; c < 16; c++) {
    int buf = c & 1;
    __syncthreads();  // drains tile-c DMA; fences buf^1 readers from iter c-1
    if (c < 15) {
      gload_lds16(Kbase + (size_t)((c + 1) * 64 + srow + lrow) * 3072 + lchunk * 8, &Ks[buf ^ 1][srow * 64]);
      gload_lds16(vtb + (size_t)(srow + lrow) * 1024 + (c + 1) * 64 + lchunk * 8, &Vs[buf ^ 1][srow * 64]);
    }
    f32x4 s[4] = {};
    #pragma unroll
    for (int kh = 0; kh < 2; kh++)
      #pragma unroll
      for (int j = 0; j < 4; j++) {
        int row = j * 16 + l16;
        int pc = (kh * 4 + quad) ^ (row & 7);
        short8 kb = *(const short8*)(&Ks[buf][row * 64 + pc * 8]);
        s[j] = MFMA_BF16(qa[kh], kb, s[j], 0, 0, 0);
      }
    #pragma unroll
    for (int j = 0; j < 4; j++)
      #pragma unroll
      for (int rp = 0; rp < 4; rp += 2) {
        float p0 = exp2f(s[j][rp]     * 0.18033688011112042f);  // 2^(s*log2e/8)
        float p1 = exp2f(s[j][rp + 1] * 0.18033688011112042f);
        l_acc[rp] += p0;
        l_acc[rp + 1] += p1;
        u32 pk;
        asm("v_cvt_pk_bf16_f32 %0, %1, %2" : "=v"(pk) : "v"(p0), "v"(p1));
        Plds[wave][quad * 4 + rp][j * 16 + l16]     = (u16)pk;
        Plds[wave][quad * 4 + rp + 1][j * 16 + l16] = (u16)(pk >> 16);
      }
    #pragma unroll
    for (int kh = 0; kh < 2; kh++) {
      short8 pa = *(const short8*)(&Plds[wave][l16][kh * 32 + quad * 8]);
      #pragma unroll
      for (int d4 = 0; d4 < 4; d4++) {
        int row = d4 * 16 + l16;
        int pc = (kh * 4 + quad) ^ (row & 7);
        short8 vb = *(const short8*)(&Vs[buf][row * 64 + pc * 8]);
        o[d4] = MFMA_BF16(pa, vb, o[d4], 0, 0, 0);
      }
    }
  }
  #pragma unroll
  for (int off = 1; off < 16; off <<= 1)
    #pragma unroll
    for (int r = 0; r < 4; r++) l_acc[r] += __shfl_xor(l_acc[r], off);
  #pragma unroll
  for (int r = 0; r < 4; r++) {
    float inv = 1.0f / l_acc[r];
    size_t row = (size_t)b * 1024 + q0 + wave * 16 + quad * 4 + r;
    #pragma unroll
    for (int d4 = 0; d4 < 4; d4++) {
      int col = (bh & 15) * 64 + d4 * 16 + l16;
      ctx[row * 1024 + col] = f2b(o[d4][r] * inv);
    }
  }
}

// ---------------- launch ----------------
extern "C" void kernel_launch(void* const* d_in, const int* in_sizes, int n_in,
                              void* d_out, int out_size, void* d_ws, size_t ws_size,
                              hipStream_t stream) {
  const float* x   = (const float*)d_in[0];
  const float* Wq  = (const float*)d_in[1];  const float* bq  = (const float*)d_in[2];
  const float* Wk  = (const float*)d_in[3];  const float* bk  = (const float*)d_in[4];
  const float* Wv  = (const float*)d_in[5];  const float* bv  = (const float*)d_in[6];
  const float* Wo  = (const float*)d_in[7];  const float* bo  = (const float*)d_in[8];
  const float* W1  = (const float*)d_in[9];  const float* b1  = (const float*)d_in[10];
  const float* W2  = (const float*)d_in[11]; const float* b2  = (const float*)d_in[12];
  const float* g1  = (const float*)d_in[13]; const float* be1 = (const float*)d_in[14];
  const float* g2  = (const float*)d_in[15]; const float* be2 = (const float*)d_in[16];

  char* ws = (char*)d_ws;
  const size_t MB = 1024 * 1024;
  u16* h1    = (u16*)(ws + 0 * MB);
  u16* qkv   = (u16*)(ws + 16 * MB);
  u16* x1    = (u16*)(ws + 16 * MB);
  u16* h2    = (u16*)(ws + 32 * MB);
  u16* W2T   = (u16*)(ws + 48 * MB);
  u16* WqkvT = (u16*)(ws + 64 * MB);
  u16* WoT   = (u16*)(ws + 70 * MB);
  u16* W1T   = (u16*)(ws + 72 * MB);
  float* bqkv = (float*)(ws + 80 * MB);
  u16* h3f   = (u16*)(ws + 80 * MB);
  u16* vt    = h1;
  u16* ctx   = (u16*)d_out;
  float* out = (float*)d_out;

  transpose_k<<<dim3(32, 32), 256, 0, stream>>>(Wq, WqkvT, 1024, 1024);
  transpose_k<<<dim3(32, 32), 256, 0, stream>>>(Wk, WqkvT + (size_t)1024 * 1024, 1024, 1024);
  transpose_k<<<dim3(32, 32), 256, 0, stream>>>(Wv, WqkvT + (size_t)2048 * 1024, 1024, 1024);
  transpose_k<<<dim3(32, 32), 256, 0, stream>>>(Wo, WoT, 1024, 1024);
  transpose_k<<<dim3(128, 32), 256, 0, stream>>>(W1, W1T, 1024, 4096);
  cat3_k<<<12, 256, 0, stream>>>(bq, bk, bv, bqkv);

  ln_k<1><<<8192, 256, 0, stream>>>(x, g1, be1, h1);

  gemm256n_k<0, 0, 0><<<dim3(32, 24), 512, 0, stream>>>(h1, WqkvT, bqkv, nullptr, qkv,
                                                        8192, 3072, 1024, 3072);   // fused QKV (3/CU exact)

  vtrans_k<<<dim3(64, 128), 256, 0, stream>>>(qkv, vt);                            // vt = h1 (dead)

  attn_k<<<dim3(128, 8), 512, 0, stream>>>(qkv, vt, ctx);                          // ctx = d_out[0,16M)

  gemm256n_k<0, 2, 0><<<dim3(32, 8), 512, 0, stream>>>(ctx, WoT, bo, x, x1,
                                                       8192, 1024, 1024, 1024);    // x1 (+fp32 x)

  transpose_k<<<dim3(32, 128), 256, 0, stream>>>(W2, W2T, 4096, 1024);             // into dead v region

  ln_k<0><<<8192, 256, 0, stream>>>(x1, g2, be2, h2);

  gemm256_k<1, 0, 0><<<dim3(32, 16), 512, 0, stream>>>(h2, W1T, b1, nullptr, h3f,
                                                       8192, 4096, 1024, 4096);    // FFN1 + GELU
  gemm256n_k<0, 1, 1><<<dim3(32, 8), 512, 0, stream>>>(h3f, W2T, b2, x1, out,
                                                       8192, 1024, 4096, 1024);    // FFN2 + resid

  (void)in_sizes; (void)n_in; (void)out_size; (void)ws_size;
}

// Round 13
// 478.207 us; speedup vs baseline: 1.0573x; 1.0401x over previous
//
#include <hip/hip_runtime.h>
#include <hip/hip_bf16.h>
#include <math.h>
#include <stdint.h>

typedef unsigned short u16;
typedef unsigned int u32;
typedef __attribute__((ext_vector_type(8))) short short8;   // 8 bf16 = 4 VGPRs (MFMA A/B frag)
typedef __attribute__((ext_vector_type(4))) float f32x4;    // MFMA C/D frag

__device__ __forceinline__ float b2f(u16 u) {
  union { u32 i; float f; } v; v.i = ((u32)u) << 16; return v.f;
}
__device__ __forceinline__ u16 f2b(float f) {
  union { float f; u32 i; } v; v.f = f;
  return (u16)((v.i + 0x7FFFu + ((v.i >> 16) & 1u)) >> 16);  // RNE
}

// async global->LDS DMA, 16B per lane; LDS dest = wave-uniform base + lane*16B
__device__ __forceinline__ void gload_lds16(const u16* g, u16* l) {
  __builtin_amdgcn_global_load_lds((const __attribute__((address_space(1))) void*)g,
                                   (__attribute__((address_space(3))) void*)l, 16, 0, 0);
}

#define LD8(p) (*(const short8*)(p))
#define MFMA_BF16 __builtin_amdgcn_mfma_f32_16x16x32_bf16

// ---------------- device helpers for fused prep/tail kernels ----------------
__device__ __forceinline__ void do_transpose(const float* __restrict__ in, u16* __restrict__ out,
                                             int K, int N, int k0, int n0, int tx, int ty,
                                             u16 (*tile)[33]) {
  #pragma unroll
  for (int i = ty; i < 32; i += 8)
    tile[i][tx] = f2b(in[(size_t)(k0 + i) * N + n0 + tx]);
  __syncthreads();
  #pragma unroll
  for (int i = ty; i < 32; i += 8)
    out[(size_t)(n0 + i) * K + k0 + tx] = tile[tx][i];
}

__device__ __forceinline__ void do_ln(const void* __restrict__ xv, int fp32in,
                                      const float* __restrict__ g, const float* __restrict__ be,
                                      u16* __restrict__ out, int row, int t,
                                      float* sb, float* ssb) {
  float f0, f1, f2, f3;
  if (fp32in) {
    const float* xr = (const float*)xv + (size_t)row * 1024;
    float4 x4 = *(const float4*)(xr + t * 4);
    f0 = x4.x; f1 = x4.y; f2 = x4.z; f3 = x4.w;
  } else {
    const u16* xr = (const u16*)xv + (size_t)row * 1024;
    ushort4 x4 = *(const ushort4*)(xr + t * 4);
    f0 = b2f(x4.x); f1 = b2f(x4.y); f2 = b2f(x4.z); f3 = b2f(x4.w);
  }
  float s = f0 + f1 + f2 + f3;
  float ss = f0 * f0 + f1 * f1 + f2 * f2 + f3 * f3;
  #pragma unroll
  for (int off = 32; off > 0; off >>= 1) { s += __shfl_down(s, off); ss += __shfl_down(ss, off); }
  if ((t & 63) == 0) { sb[t >> 6] = s; ssb[t >> 6] = ss; }
  __syncthreads();
  s = sb[0] + sb[1] + sb[2] + sb[3];
  ss = ssb[0] + ssb[1] + ssb[2] + ssb[3];
  float mu = s * (1.0f / 1024.0f);
  float var = ss * (1.0f / 1024.0f) - mu * mu;
  float rstd = rsqrtf(var + 1e-5f);
  float4 gv = *(const float4*)(g + t * 4);
  float4 bv = *(const float4*)(be + t * 4);
  ushort4 o;
  o.x = f2b((f0 - mu) * rstd * gv.x + bv.x);
  o.y = f2b((f1 - mu) * rstd * gv.y + bv.y);
  o.z = f2b((f2 - mu) * rstd * gv.z + bv.z);
  o.w = f2b((f3 - mu) * rstd * gv.w + bv.w);
  *(ushort4*)(out + (size_t)row * 1024 + t * 4) = o;
}

// ---------------- prep_k: Wq/Wk/Wv/Wo/W1 transposes + cat3 + ln1, one launch ----------------
// grid 16396 x 256. Block-range decode: [0,4096) 1024-sq transposes; [4096,8192) W1;
// [8192,8204) cat3; [8204,16396) ln1 rows. All jobs independent; saves 6 dispatch gaps.
__global__ __launch_bounds__(256) void prep_k(const float* __restrict__ Wq, const float* __restrict__ Wk,
                                              const float* __restrict__ Wv, const float* __restrict__ Wo,
                                              const float* __restrict__ W1,
                                              u16* __restrict__ WqkvT, u16* __restrict__ WoT,
                                              u16* __restrict__ W1T,
                                              const float* __restrict__ bq, const float* __restrict__ bk,
                                              const float* __restrict__ bv, float* __restrict__ bqkv,
                                              const float* __restrict__ x, const float* __restrict__ g1,
                                              const float* __restrict__ be1, u16* __restrict__ h1) {
  __shared__ u16 tile[32][33];
  __shared__ float sb[4], ssb[4];
  int bid = blockIdx.x, t = threadIdx.x;
  int tx = t & 31, ty = t >> 5;
  if (bid < 4096) {
    int which = bid >> 10, tt = bid & 1023;
    int n0 = (tt & 31) * 32, k0 = (tt >> 5) * 32;
    const float* in = which == 0 ? Wq : which == 1 ? Wk : which == 2 ? Wv : Wo;
    u16* out = which == 3 ? WoT : WqkvT + (size_t)which * 1024 * 1024;
    do_transpose(in, out, 1024, 1024, k0, n0, tx, ty, tile);
  } else if (bid < 8192) {
    int tt = bid - 4096;
    int n0 = (tt & 127) * 32, k0 = (tt >> 7) * 32;
    do_transpose(W1, W1T, 1024, 4096, k0, n0, tx, ty, tile);
  } else if (bid < 8204) {
    int i = (bid - 8192) * 256 + t;
    bqkv[i] = i < 1024 ? bq[i] : (i < 2048 ? bk[i - 1024] : bv[i - 2048]);
  } else {
    do_ln(x, 1, g1, be1, h1, bid - 8204, t, sb, ssb);
  }
}

// ---------------- tail_k: W2 transpose + ln2, one launch (runs after attn + O-proj) ------------
// grid 12288 x 256: [0,4096) W2 (K=4096,N=1024) -> W2T (into dead qkv region); [4096,12288) ln2.
__global__ __launch_bounds__(256) void tail_k(const float* __restrict__ W2, u16* __restrict__ W2T,
                                              const u16* __restrict__ x1, const float* __restrict__ g2,
                                              const float* __restrict__ be2, u16* __restrict__ h2) {
  __shared__ u16 tile[32][33];
  __shared__ float sb[4], ssb[4];
  int bid = blockIdx.x, t = threadIdx.x;
  int tx = t & 31, ty = t >> 5;
  if (bid < 4096) {
    int n0 = (bid & 31) * 32, k0 = (bid >> 5) * 32;
    do_transpose(W2, W2T, 4096, 1024, k0, n0, tx, ty, tile);
  } else {
    do_ln(x1, 0, g2, be2, h2, bid - 4096, t, sb, ssb);
  }
}

// ---------------- per-head V transpose from strided qkv: v[s][2048+h*64+d] -> vt[(bh*64+d)][s] ----------------
__global__ __launch_bounds__(256) void vtrans_k(const u16* __restrict__ qkv, u16* __restrict__ vt) {
  __shared__ u16 tile[32][33];
  int bh = blockIdx.y, b = bh >> 4, h = bh & 15;
  int s0 = (blockIdx.x & 31) * 32, d0 = (blockIdx.x >> 5) * 32;
  int tx = threadIdx.x & 31, ty = threadIdx.x >> 5;
  #pragma unroll
  for (int i = ty; i < 32; i += 8)
    tile[i][tx] = qkv[(size_t)(b * 1024 + s0 + i) * 3072 + 2048 + h * 64 + d0 + tx];
  __syncthreads();
  #pragma unroll
  for (int i = ty; i < 32; i += 8)
    vt[(size_t)(bh * 64 + d0 + i) * 1024 + s0 + tx] = tile[tx][i];
}

// ======================= gemm256_k: BK=64 4-phase schedule (QKV + FFN1) ========================
// r10-proven. BM=BN=256 (traffic-minimal for K=1024 wide-N), 8 waves (2M x 4N), per-wave 128x64
// (acc[8][4]), 2 LDS buffers (128KB). P0/P1 stage A/B of tile tt+1; P2/P3 pure compute; boundary
// vmcnt(0) retires loads issued >=2 phases earlier (already landed -> cheap). Swizzle: 128B row
// pitch, chunk XOR (row&7), 0 conflicts measured.
template<int ACT, int RESID, int OUTF32>
__global__ __launch_bounds__(512, 2) void gemm256_k(const u16* __restrict__ A, const u16* __restrict__ Bt,
                                                    const float* __restrict__ bias, const void* __restrict__ resid,
                                                    void* __restrict__ Cv, int M, int N, int K, int ldc) {
  __shared__ u16 As[2][256 * 64];   // 2 x 32KB
  __shared__ u16 Bs[2][256 * 64];   // 2 x 32KB
  int Ny = N >> 8;
  int lin = blockIdx.y * 32 + blockIdx.x;
  int c8 = lin & 7, sblk = lin >> 3;
  int mq = sblk / Ny;
  int m0 = ((mq << 3) | c8) << 8;
  int n0 = (sblk - mq * Ny) << 8;
  int t = threadIdx.x;
  int wave = t >> 6, lane = t & 63, quad = lane >> 4, l16 = lane & 15;
  int wm = (wave >> 2) << 7;            // 0 | 128
  int wn = (wave & 3) << 6;             // 0..192
  f32x4 acc[8][4] = {};
  int lrow = lane >> 3;                        // 0..7
  int lchunk = (lane & 7) ^ lrow;              // src chunk = logical ^ (row&7)
  const u16* Ab = A + (size_t)(m0 + wave * 32 + lrow) * K + lchunk * 8;
  const u16* Bb = Bt + (size_t)(n0 + wave * 32 + lrow) * K + lchunk * 8;
  const int sbase = wave * 32 * 64;            // wave's staging slab base (elements); +g*8*64
  const int x7 = l16 & 7;
  const int rdA = (wm + l16) * 64;             // + i*1024 + cswz
  const int rdB = (wn + l16) * 64;             // + j*1024 + cswz
  const int cz0 = (quad ^ x7) * 8;             // kk=0: logical chunk = quad
  const int cz1 = ((4 + quad) ^ x7) * 8;       // kk=1: logical chunk = 4+quad
  const int niter = K >> 6;
  // ---- prologue: stage tile 0 into buf0 (8 gloads/wave) ----
  #pragma unroll
  for (int g = 0; g < 4; g++) {
    gload_lds16(Ab + (size_t)g * 8 * K, &As[0][sbase + g * 8 * 64]);
    gload_lds16(Bb + (size_t)g * 8 * K, &Bs[0][sbase + g * 8 * 64]);
  }
  asm volatile("s_waitcnt vmcnt(0)" ::: "memory");
  __builtin_amdgcn_s_barrier();
  __builtin_amdgcn_sched_barrier(0);
  for (int tt = 0; tt < niter; tt++) {
    int buf = tt & 1;
    const bool pf = (tt + 1 < niter);
    const int kpf = (tt + 1) << 6;
    const u16* Ac = &As[buf][0];
    const u16* Bc = &Bs[buf][0];
    u16* Aw = &As[buf ^ 1][0];
    u16* Bw = &Bs[buf ^ 1][0];
    short8 a0, a1, a2, a3, a4, a5, a6, a7, b0, b1, b2, b3;
    // ---------- P0: kk=0 i0-3 + all b ; stage A(tile tt+1) ----------
    a0 = LD8(Ac + rdA + cz0);
    a1 = LD8(Ac + rdA + 1024 + cz0);
    a2 = LD8(Ac + rdA + 2048 + cz0);
    a3 = LD8(Ac + rdA + 3072 + cz0);
    b0 = LD8(Bc + rdB + cz0);
    b1 = LD8(Bc + rdB + 1024 + cz0);
    b2 = LD8(Bc + rdB + 2048 + cz0);
    b3 = LD8(Bc + rdB + 3072 + cz0);
    if (pf) {
      #pragma unroll
      for (int g = 0; g < 4; g++)
        gload_lds16(Ab + kpf + (size_t)g * 8 * K, Aw + sbase + g * 8 * 64);
    }
    __builtin_amdgcn_s_barrier();
    asm volatile("s_waitcnt lgkmcnt(0)" ::: "memory");
    __builtin_amdgcn_sched_barrier(0);
    __builtin_amdgcn_s_setprio(1);
    acc[0][0] = MFMA_BF16(a0, b0, acc[0][0], 0, 0, 0);
    acc[0][1] = MFMA_BF16(a0, b1, acc[0][1], 0, 0, 0);
    acc[0][2] = MFMA_BF16(a0, b2, acc[0][2], 0, 0, 0);
    acc[0][3] = MFMA_BF16(a0, b3, acc[0][3], 0, 0, 0);
    acc[1][0] = MFMA_BF16(a1, b0, acc[1][0], 0, 0, 0);
    acc[1][1] = MFMA_BF16(a1, b1, acc[1][1], 0, 0, 0);
    acc[1][2] = MFMA_BF16(a1, b2, acc[1][2], 0, 0, 0);
    acc[1][3] = MFMA_BF16(a1, b3, acc[1][3], 0, 0, 0);
    acc[2][0] = MFMA_BF16(a2, b0, acc[2][0], 0, 0, 0);
    acc[2][1] = MFMA_BF16(a2, b1, acc[2][1], 0, 0, 0);
    acc[2][2] = MFMA_BF16(a2, b2, acc[2][2], 0, 0, 0);
    acc[2][3] = MFMA_BF16(a2, b3, acc[2][3], 0, 0, 0);
    acc[3][0] = MFMA_BF16(a3, b0, acc[3][0], 0, 0, 0);
    acc[3][1] = MFMA_BF16(a3, b1, acc[3][1], 0, 0, 0);
    acc[3][2] = MFMA_BF16(a3, b2, acc[3][2], 0, 0, 0);
    acc[3][3] = MFMA_BF16(a3, b3, acc[3][3], 0, 0, 0);
    __builtin_amdgcn_s_setprio(0);
    __builtin_amdgcn_s_barrier();
    __builtin_amdgcn_sched_barrier(0);
    // ---------- P1: kk=0 i4-7 ; stage B(tile tt+1) ----------
    a4 = LD8(Ac + rdA + 4096 + cz0);
    a5 = LD8(Ac + rdA + 5120 + cz0);
    a6 = LD8(Ac + rdA + 6144 + cz0);
    a7 = LD8(Ac + rdA + 7168 + cz0);
    if (pf) {
      #pragma unroll
      for (int g = 0; g < 4; g++)
        gload_lds16(Bb + kpf + (size_t)g * 8 * K, Bw + sbase + g * 8 * 64);
    }
    __builtin_amdgcn_s_barrier();
    asm volatile("s_waitcnt lgkmcnt(0)" ::: "memory");
    __builtin_amdgcn_sched_barrier(0);
    __builtin_amdgcn_s_setprio(1);
    acc[4][0] = MFMA_BF16(a4, b0, acc[4][0], 0, 0, 0);
    acc[4][1] = MFMA_BF16(a4, b1, acc[4][1], 0, 0, 0);
    acc[4][2] = MFMA_BF16(a4, b2, acc[4][2], 0, 0, 0);
    acc[4][3] = MFMA_BF16(a4, b3, acc[4][3], 0, 0, 0);
    acc[5][0] = MFMA_BF16(a5, b0, acc[5][0], 0, 0, 0);
    acc[5][1] = MFMA_BF16(a5, b1, acc[5][1], 0, 0, 0);
    acc[5][2] = MFMA_BF16(a5, b2, acc[5][2], 0, 0, 0);
    acc[5][3] = MFMA_BF16(a5, b3, acc[5][3], 0, 0, 0);
    acc[6][0] = MFMA_BF16(a6, b0, acc[6][0], 0, 0, 0);
    acc[6][1] = MFMA_BF16(a6, b1, acc[6][1], 0, 0, 0);
    acc[6][2] = MFMA_BF16(a6, b2, acc[6][2], 0, 0, 0);
    acc[6][3] = MFMA_BF16(a6, b3, acc[6][3], 0, 0, 0);
    acc[7][0] = MFMA_BF16(a7, b0, acc[7][0], 0, 0, 0);
    acc[7][1] = MFMA_BF16(a7, b1, acc[7][1], 0, 0, 0);
    acc[7][2] = MFMA_BF16(a7, b2, acc[7][2], 0, 0, 0);
    acc[7][3] = MFMA_BF16(a7, b3, acc[7][3], 0, 0, 0);
    __builtin_amdgcn_s_setprio(0);
    __builtin_amdgcn_s_barrier();
    __builtin_amdgcn_sched_barrier(0);
    // ---------- P2: kk=1 i0-3 + all b ----------
    a0 = LD8(Ac + rdA + cz1);
    a1 = LD8(Ac + rdA + 1024 + cz1);
    a2 = LD8(Ac + rdA + 2048 + cz1);
    a3 = LD8(Ac + rdA + 3072 + cz1);
    b0 = LD8(Bc + rdB + cz1);
    b1 = LD8(Bc + rdB + 1024 + cz1);
    b2 = LD8(Bc + rdB + 2048 + cz1);
    b3 = LD8(Bc + rdB + 3072 + cz1);
    __builtin_amdgcn_s_barrier();
    asm volatile("s_waitcnt lgkmcnt(0)" ::: "memory");
    __builtin_amdgcn_sched_barrier(0);
    __builtin_amdgcn_s_setprio(1);
    acc[0][0] = MFMA_BF16(a0, b0, acc[0][0], 0, 0, 0);
    acc[0][1] = MFMA_BF16(a0, b1, acc[0][1], 0, 0, 0);
    acc[0][2] = MFMA_BF16(a0, b2, acc[0][2], 0, 0, 0);
    acc[0][3] = MFMA_BF16(a0, b3, acc[0][3], 0, 0, 0);
    acc[1][0] = MFMA_BF16(a1, b0, acc[1][0], 0, 0, 0);
    acc[1][1] = MFMA_BF16(a1, b1, acc[1][1], 0, 0, 0);
    acc[1][2] = MFMA_BF16(a1, b2, acc[1][2], 0, 0, 0);
    acc[1][3] = MFMA_BF16(a1, b3, acc[1][3], 0, 0, 0);
    acc[2][0] = MFMA_BF16(a2, b0, acc[2][0], 0, 0, 0);
    acc[2][1] = MFMA_BF16(a2, b1, acc[2][1], 0, 0, 0);
    acc[2][2] = MFMA_BF16(a2, b2, acc[2][2], 0, 0, 0);
    acc[2][3] = MFMA_BF16(a2, b3, acc[2][3], 0, 0, 0);
    acc[3][0] = MFMA_BF16(a3, b0, acc[3][0], 0, 0, 0);
    acc[3][1] = MFMA_BF16(a3, b1, acc[3][1], 0, 0, 0);
    acc[3][2] = MFMA_BF16(a3, b2, acc[3][2], 0, 0, 0);
    acc[3][3] = MFMA_BF16(a3, b3, acc[3][3], 0, 0, 0);
    __builtin_amdgcn_s_setprio(0);
    __builtin_amdgcn_s_barrier();
    __builtin_amdgcn_sched_barrier(0);
    // ---------- P3: kk=1 i4-7 ; K-tile boundary ----------
    a4 = LD8(Ac + rdA + 4096 + cz1);
    a5 = LD8(Ac + rdA + 5120 + cz1);
    a6 = LD8(Ac + rdA + 6144 + cz1);
    a7 = LD8(Ac + rdA + 7168 + cz1);
    __builtin_amdgcn_s_barrier();
    asm volatile("s_waitcnt lgkmcnt(0)" ::: "memory");
    __builtin_amdgcn_sched_barrier(0);
    __builtin_amdgcn_s_setprio(1);
    acc[4][0] = MFMA_BF16(a4, b0, acc[4][0], 0, 0, 0);
    acc[4][1] = MFMA_BF16(a4, b1, acc[4][1], 0, 0, 0);
    acc[4][2] = MFMA_BF16(a4, b2, acc[4][2], 0, 0, 0);
    acc[4][3] = MFMA_BF16(a4, b3, acc[4][3], 0, 0, 0);
    acc[5][0] = MFMA_BF16(a5, b0, acc[5][0], 0, 0, 0);
    acc[5][1] = MFMA_BF16(a5, b1, acc[5][1], 0, 0, 0);
    acc[5][2] = MFMA_BF16(a5, b2, acc[5][2], 0, 0, 0);
    acc[5][3] = MFMA_BF16(a5, b3, acc[5][3], 0, 0, 0);
    acc[6][0] = MFMA_BF16(a6, b0, acc[6][0], 0, 0, 0);
    acc[6][1] = MFMA_BF16(a6, b1, acc[6][1], 0, 0, 0);
    acc[6][2] = MFMA_BF16(a6, b2, acc[6][2], 0, 0, 0);
    acc[6][3] = MFMA_BF16(a6, b3, acc[6][3], 0, 0, 0);
    acc[7][0] = MFMA_BF16(a7, b0, acc[7][0], 0, 0, 0);
    acc[7][1] = MFMA_BF16(a7, b1, acc[7][1], 0, 0, 0);
    acc[7][2] = MFMA_BF16(a7, b2, acc[7][2], 0, 0, 0);
    acc[7][3] = MFMA_BF16(a7, b3, acc[7][3], 0, 0, 0);
    __builtin_amdgcn_s_setprio(0);
    if (pf) {
      asm volatile("s_waitcnt vmcnt(0)" ::: "memory");  // loads issued >=2 phases ago
      __builtin_amdgcn_s_barrier();
      __builtin_amdgcn_sched_barrier(0);
    }
  }
  // epilogue: C/D layout col=lane&15, row=quad*4+reg
  float bcol[4];
  #pragma unroll
  for (int j = 0; j < 4; j++) bcol[j] = bias[n0 + wn + j * 16 + l16];
  #pragma unroll
  for (int i = 0; i < 8; i++) {
    #pragma unroll
    for (int r = 0; r < 4; r++) {
      int row = m0 + wm + i * 16 + quad * 4 + r;
      #pragma unroll
      for (int j = 0; j < 4; j++) {
        int col = n0 + wn + j * 16 + l16;
        float v = acc[i][j][r] + bcol[j];
        if (ACT == 1) {
          float e = v * (2.3022082f + 0.1029431f * v * v);
          float tt2 = exp2f(fminf(e, 80.0f));
          v = v * tt2 / (tt2 + 1.0f);
        }
        if (RESID == 1) v += b2f(((const u16*)resid)[(size_t)row * N + col]);
        if (RESID == 2) v += ((const float*)resid)[(size_t)row * N + col];
        if (OUTF32) ((float*)Cv)[(size_t)row * ldc + col] = v;
        else        ((u16*)Cv)[(size_t)row * ldc + col] = f2b(v);
      }
    }
  }
}

// ======================= gemm256n_k: BM=256 BN=128, 3-buf, counted vmcnt (O-proj + FFN2) =======
// Measured r7: 808 TF (FFN2 K=4096), ~750 TF (O-proj). Exact 1-round grid at N=1024.
template<int ACT, int RESID, int OUTF32>
__global__ __launch_bounds__(512, 2) void gemm256n_k(const u16* __restrict__ A, const u16* __restrict__ Bt,
                                                     const float* __restrict__ bias, const void* __restrict__ resid,
                                                     void* __restrict__ Cv, int M, int N, int K, int ldc) {
  __shared__ u16 As[3][256 * 64];   // 3 x 32KB
  __shared__ u16 Bs[3][128 * 64];   // 3 x 16KB
  int Ny = N >> 7;
  int lin = blockIdx.y * 32 + blockIdx.x;
  int c8 = lin & 7, sblk = lin >> 3;
  int mq = sblk / Ny;
  int m0 = ((mq << 3) | c8) << 8;
  int n0 = (sblk - mq * Ny) << 7;
  int t = threadIdx.x;
  int wave = t >> 6, lane = t & 63, quad = lane >> 4, l16 = lane & 15;
  int wm = (wave >> 1) << 6;            // 0 | 64 | 128 | 192
  int wn = (wave & 1) << 6;             // 0 | 64
  f32x4 acc[4][4] = {};
  int lrow = lane >> 3;                        // 0..7
  int lchunk = (lane & 7) ^ lrow;              // src chunk = logical ^ (row&7)
  const u16* Ab = A + (size_t)(m0 + wave * 32 + lrow) * K + lchunk * 8;
  const u16* Bb = Bt + (size_t)(n0 + wave * 16 + lrow) * K + lchunk * 8;
  const int sbA = wave * 32 * 64;              // A staging slab (4 instrs x 8 rows)
  const int sbB = wave * 16 * 64;              // B staging slab (2 instrs x 8 rows)
  const int x7 = l16 & 7;
  const int rdA = (wm + l16) * 64;             // + i*1024 + cz
  const int rdB = (wn + l16) * 64;             // + j*1024 + cz
  const int cz0 = (quad ^ x7) * 8;
  const int cz1 = ((4 + quad) ^ x7) * 8;
  const int niter = K >> 6;
  // ---- prologue: stage tiles 0,1 (12 gloads/wave) ----
  #pragma unroll
  for (int p = 0; p < 2; p++) {
    #pragma unroll
    for (int g = 0; g < 4; g++)
      gload_lds16(Ab + (p << 6) + (size_t)g * 8 * K, &As[p][sbA + g * 8 * 64]);
    #pragma unroll
    for (int g = 0; g < 2; g++)
      gload_lds16(Bb + (p << 6) + (size_t)g * 8 * K, &Bs[p][sbB + g * 8 * 64]);
  }
  asm volatile("s_waitcnt vmcnt(6)" ::: "memory");   // tile0 landed; tile1 in flight
  __builtin_amdgcn_s_barrier();
  __builtin_amdgcn_sched_barrier(0);
  int cur = 0;
  for (int tt = 0; tt < niter; tt++) {
    int wb = cur + 2; if (wb >= 3) wb -= 3;
    const bool pf = (tt + 2 < niter);
    const int kpf = (tt + 2) << 6;
    const u16* Ac = &As[cur][0];
    const u16* Bc = &Bs[cur][0];
    short8 a0, a1, a2, a3, b0, b1, b2, b3;
    // ---------- P0: kk=0 (a0-3, b0-3) ; stage A(tile tt+2) ----------
    a0 = LD8(Ac + rdA + cz0);
    a1 = LD8(Ac + rdA + 1024 + cz0);
    a2 = LD8(Ac + rdA + 2048 + cz0);
    a3 = LD8(Ac + rdA + 3072 + cz0);
    b0 = LD8(Bc + rdB + cz0);
    b1 = LD8(Bc + rdB + 1024 + cz0);
    b2 = LD8(Bc + rdB + 2048 + cz0);
    b3 = LD8(Bc + rdB + 3072 + cz0);
    if (pf) {
      #pragma unroll
      for (int g = 0; g < 4; g++)
        gload_lds16(Ab + kpf + (size_t)g * 8 * K, &As[wb][sbA + g * 8 * 64]);
    }
    __builtin_amdgcn_s_barrier();
    asm volatile("s_waitcnt lgkmcnt(0)" ::: "memory");
    __builtin_amdgcn_sched_barrier(0);
    __builtin_amdgcn_s_setprio(1);
    acc[0][0] = MFMA_BF16(a0, b0, acc[0][0], 0, 0, 0);
    acc[0][1] = MFMA_BF16(a0, b1, acc[0][1], 0, 0, 0);
    acc[0][2] = MFMA_BF16(a0, b2, acc[0][2], 0, 0, 0);
    acc[0][3] = MFMA_BF16(a0, b3, acc[0][3], 0, 0, 0);
    acc[1][0] = MFMA_BF16(a1, b0, acc[1][0], 0, 0, 0);
    acc[1][1] = MFMA_BF16(a1, b1, acc[1][1], 0, 0, 0);
    acc[1][2] = MFMA_BF16(a1, b2, acc[1][2], 0, 0, 0);
    acc[1][3] = MFMA_BF16(a1, b3, acc[1][3], 0, 0, 0);
    acc[2][0] = MFMA_BF16(a2, b0, acc[2][0], 0, 0, 0);
    acc[2][1] = MFMA_BF16(a2, b1, acc[2][1], 0, 0, 0);
    acc[2][2] = MFMA_BF16(a2, b2, acc[2][2], 0, 0, 0);
    acc[2][3] = MFMA_BF16(a2, b3, acc[2][3], 0, 0, 0);
    acc[3][0] = MFMA_BF16(a3, b0, acc[3][0], 0, 0, 0);
    acc[3][1] = MFMA_BF16(a3, b1, acc[3][1], 0, 0, 0);
    acc[3][2] = MFMA_BF16(a3, b2, acc[3][2], 0, 0, 0);
    acc[3][3] = MFMA_BF16(a3, b3, acc[3][3], 0, 0, 0);
    __builtin_amdgcn_s_setprio(0);
    __builtin_amdgcn_s_barrier();
    __builtin_amdgcn_sched_barrier(0);
    // ---------- P1: kk=1 (a,b re-read) ; stage B(tile tt+2) ----------
    a0 = LD8(Ac + rdA + cz1);
    a1 = LD8(Ac + rdA + 1024 + cz1);
    a2 = LD8(Ac + rdA + 2048 + cz1);
    a3 = LD8(Ac + rdA + 3072 + cz1);
    b0 = LD8(Bc + rdB + cz1);
    b1 = LD8(Bc + rdB + 1024 + cz1);
    b2 = LD8(Bc + rdB + 2048 + cz1);
    b3 = LD8(Bc + rdB + 3072 + cz1);
    if (pf) {
      #pragma unroll
      for (int g = 0; g < 2; g++)
        gload_lds16(Bb + kpf + (size_t)g * 8 * K, &Bs[wb][sbB + g * 8 * 64]);
    }
    __builtin_amdgcn_s_barrier();
    asm volatile("s_waitcnt lgkmcnt(0)" ::: "memory");
    __builtin_amdgcn_sched_barrier(0);
    __builtin_amdgcn_s_setprio(1);
    acc[0][0] = MFMA_BF16(a0, b0, acc[0][0], 0, 0, 0);
    acc[0][1] = MFMA_BF16(a0, b1, acc[0][1], 0, 0, 0);
    acc[0][2] = MFMA_BF16(a0, b2, acc[0][2], 0, 0, 0);
    acc[0][3] = MFMA_BF16(a0, b3, acc[0][3], 0, 0, 0);
    acc[1][0] = MFMA_BF16(a1, b0, acc[1][0], 0, 0, 0);
    acc[1][1] = MFMA_BF16(a1, b1, acc[1][1], 0, 0, 0);
    acc[1][2] = MFMA_BF16(a1, b2, acc[1][2], 0, 0, 0);
    acc[1][3] = MFMA_BF16(a1, b3, acc[1][3], 0, 0, 0);
    acc[2][0] = MFMA_BF16(a2, b0, acc[2][0], 0, 0, 0);
    acc[2][1] = MFMA_BF16(a2, b1, acc[2][1], 0, 0, 0);
    acc[2][2] = MFMA_BF16(a2, b2, acc[2][2], 0, 0, 0);
    acc[2][3] = MFMA_BF16(a2, b3, acc[2][3], 0, 0, 0);
    acc[3][0] = MFMA_BF16(a3, b0, acc[3][0], 0, 0, 0);
    acc[3][1] = MFMA_BF16(a3, b1, acc[3][1], 0, 0, 0);
    acc[3][2] = MFMA_BF16(a3, b2, acc[3][2], 0, 0, 0);
    acc[3][3] = MFMA_BF16(a3, b3, acc[3][3], 0, 0, 0);
    __builtin_amdgcn_s_setprio(0);
    if (tt + 2 < niter) {
      asm volatile("s_waitcnt vmcnt(6)" ::: "memory");  // tile tt+1 landed; tt+2 in flight
    } else if (tt + 1 < niter) {
      asm volatile("s_waitcnt vmcnt(0)" ::: "memory");  // tail drain
    }
    if (tt + 1 < niter) {
      __builtin_amdgcn_s_barrier();
      __builtin_amdgcn_sched_barrier(0);
    }
    cur = (cur == 2) ? 0 : cur + 1;
  }
  // epilogue: C/D layout col=lane&15, row=quad*4+reg
  float bcol[4];
  #pragma unroll
  for (int j = 0; j < 4; j++) bcol[j] = bias[n0 + wn + j * 16 + l16];
  #pragma unroll
  for (int i = 0; i < 4; i++) {
    #pragma unroll
    for (int r = 0; r < 4; r++) {
      int row = m0 + wm + i * 16 + quad * 4 + r;
      #pragma unroll
      for (int j = 0; j < 4; j++) {
        int col = n0 + wn + j * 16 + l16;
        float v = acc[i][j][r] + bcol[j];
        if (ACT == 1) {
          float e = v * (2.3022082f + 0.1029431f * v * v);
          float tt2 = exp2f(fminf(e, 80.0f));
          v = v * tt2 / (tt2 + 1.0f);
        }
        if (RESID == 1) v += b2f(((const u16*)resid)[(size_t)row * N + col]);
        if (RESID == 2) v += ((const float*)resid)[(size_t)row * N + col];
        if (OUTF32) ((float*)Cv)[(size_t)row * ldc + col] = v;
        else        ((u16*)Cv)[(size_t)row * ldc + col] = f2b(v);
      }
    }
  }
}

// ---------------- Flash attention: grid (B*H, S/128); qkv strided (ld=3072) ----------------
// r10 structure (proven): 2-buffer __syncthreads skeleton, 8 waves/block covering 128 Q-rows
// (shared K/V tiles serve 2x Q rows; per-wave staging 2 gloads/iter), cvt_pk packed bf16.
__global__ __launch_bounds__(512) void attn_k(const u16* __restrict__ QKV, const u16* __restrict__ VT,
                                              u16* __restrict__ ctx) {
  int bh = blockIdx.x;
  int b = bh >> 4;
  int q0 = blockIdx.y * 128;
  int t = threadIdx.x, wave = t >> 6, lane = t & 63, quad = lane >> 4, l16 = lane & 15;
  __shared__ u16 Ks[2][64 * 64];    // [key][d], XOR-swizzled chunks
  __shared__ u16 Vs[2][64 * 64];    // [d][key-of-tile], XOR-swizzled
  __shared__ u16 Plds[8][16][72];   // per-wave P strip (wave-private)
  const size_t base = ((size_t)b * 1024) * 3072 + (size_t)(bh & 15) * 64;
  const u16* Kbase = QKV + base + 1024;
  const u16* vtb = VT + (size_t)bh * 64 * 1024;
  int lrow = lane >> 3;                  // 0..7
  int lchunk = (lane & 7) ^ lrow;        // source-permute => phys chunk = logical ^ (row&7)
  int srow = wave * 8;                   // this wave's 8-row staging slab of the 64-row tile
  short8 qa[2];  // Q A-frags: A[m=l16][k=quad*8+j], k-halves 0/32
  #pragma unroll
  for (int kh = 0; kh < 2; kh++)
    qa[kh] = *(const short8*)(QKV + base + (size_t)(q0 + wave * 16 + l16) * 3072 + kh * 32 + quad * 8);
  gload_lds16(Kbase + (size_t)(srow + lrow) * 3072 + lchunk * 8, &Ks[0][srow * 64]);
  gload_lds16(vtb + (size_t)(srow + lrow) * 1024 + lchunk * 8, &Vs[0][srow * 64]);
  f32x4 o[4] = {};
  float l_acc[4] = {0.f, 0.f, 0.f, 0.f};
  for (int c = 0; c < 16; c++) {
    int buf = c & 1;
    __syncthreads();  // drains tile-c DMA; fences buf^1 readers from iter c-1
    if (c < 15) {
      gload_lds16(Kbase + (size_t)((c + 1) * 64 + srow + lrow) * 3072 + lchunk * 8, &Ks[buf ^ 1][srow * 64]);
      gload_lds16(vtb + (size_t)(srow + lrow) * 1024 + (c + 1) * 64 + lchunk * 8, &Vs[buf ^ 1][srow * 64]);
    }
    f32x4 s[4] = {};
    #pragma unroll
    for (int kh = 0; kh < 2; kh++)
      #pragma unroll
      for (int j = 0; j < 4; j++) {
        int row = j * 16 + l16;
        int pc = (kh * 4 + quad) ^ (row & 7);
        short8 kb = *(const short8*)(&Ks[buf][row * 64 + pc * 8]);
        s[j] = MFMA_BF16(qa[kh], kb, s[j], 0, 0, 0);
      }
    #pragma unroll
    for (int j = 0; j < 4; j++)
      #pragma unroll
      for (int rp = 0; rp < 4; rp += 2) {
        float p0 = exp2f(s[j][rp]     * 0.18033688011112042f);  // 2^(s*log2e/8)
        float p1 = exp2f(s[j][rp + 1] * 0.18033688011112042f);
        l_acc[rp] += p0;
        l_acc[rp + 1] += p1;
        u32 pk;
        asm("v_cvt_pk_bf16_f32 %0, %1, %2" : "=v"(pk) : "v"(p0), "v"(p1));
        Plds[wave][quad * 4 + rp][j * 16 + l16]     = (u16)pk;
        Plds[wave][quad * 4 + rp + 1][j * 16 + l16] = (u16)(pk >> 16);
      }
    #pragma unroll
    for (int kh = 0; kh < 2; kh++) {
      short8 pa = *(const short8*)(&Plds[wave][l16][kh * 32 + quad * 8]);
      #pragma unroll
      for (int d4 = 0; d4 < 4; d4++) {
        int row = d4 * 16 + l16;
        int pc = (kh * 4 + quad) ^ (row & 7);
        short8 vb = *(const short8*)(&Vs[buf][row * 64 + pc * 8]);
        o[d4] = MFMA_BF16(pa, vb, o[d4], 0, 0, 0);
      }
    }
  }
  #pragma unroll
  for (int off = 1; off < 16; off <<= 1)
    #pragma unroll
    for (int r = 0; r < 4; r++) l_acc[r] += __shfl_xor(l_acc[r], off);
  #pragma unroll
  for (int r = 0; r < 4; r++) {
    float inv = 1.0f / l_acc[r];
    size_t row = (size_t)b * 1024 + q0 + wave * 16 + quad * 4 + r;
    #pragma unroll
    for (int d4 = 0; d4 < 4; d4++) {
      int col = (bh & 15) * 64 + d4 * 16 + l16;
      ctx[row * 1024 + col] = f2b(o[d4][r] * inv);
    }
  }
}

// ---------------- launch ----------------
// 8 launches (was 15): prep_k fuses 5 transposes + cat3 + ln1; tail_k fuses W2T + ln2.
extern "C" void kernel_launch(void* const* d_in, const int* in_sizes, int n_in,
                              void* d_out, int out_size, void* d_ws, size_t ws_size,
                              hipStream_t stream) {
  const float* x   = (const float*)d_in[0];
  const float* Wq  = (const float*)d_in[1];  const float* bq  = (const float*)d_in[2];
  const float* Wk  = (const float*)d_in[3];  const float* bk  = (const float*)d_in[4];
  const float* Wv  = (const float*)d_in[5];  const float* bv  = (const float*)d_in[6];
  const float* Wo  = (const float*)d_in[7];  const float* bo  = (const float*)d_in[8];
  const float* W1  = (const float*)d_in[9];  const float* b1  = (const float*)d_in[10];
  const float* W2  = (const float*)d_in[11]; const float* b2  = (const float*)d_in[12];
  const float* g1  = (const float*)d_in[13]; const float* be1 = (const float*)d_in[14];
  const float* g2  = (const float*)d_in[15]; const float* be2 = (const float*)d_in[16];

  char* ws = (char*)d_ws;
  const size_t MB = 1024 * 1024;
  u16* h1    = (u16*)(ws + 0 * MB);
  u16* qkv   = (u16*)(ws + 16 * MB);
  u16* x1    = (u16*)(ws + 16 * MB);
  u16* h2    = (u16*)(ws + 32 * MB);
  u16* W2T   = (u16*)(ws + 48 * MB);
  u16* WqkvT = (u16*)(ws + 64 * MB);
  u16* WoT   = (u16*)(ws + 70 * MB);
  u16* W1T   = (u16*)(ws + 72 * MB);
  float* bqkv = (float*)(ws + 80 * MB);
  u16* h3f   = (u16*)(ws + 80 * MB);
  u16* vt    = h1;
  u16* ctx   = (u16*)d_out;
  float* out = (float*)d_out;

  prep_k<<<16396, 256, 0, stream>>>(Wq, Wk, Wv, Wo, W1, WqkvT, WoT, W1T,
                                    bq, bk, bv, bqkv, x, g1, be1, h1);

  gemm256_k<0, 0, 0><<<dim3(32, 12), 512, 0, stream>>>(h1, WqkvT, bqkv, nullptr, qkv,
                                                       8192, 3072, 1024, 3072);    // fused QKV

  vtrans_k<<<dim3(64, 128), 256, 0, stream>>>(qkv, vt);                            // vt = h1 (dead)

  attn_k<<<dim3(128, 8), 512, 0, stream>>>(qkv, vt, ctx);                          // ctx = d_out[0,16M)

  gemm256n_k<0, 2, 0><<<dim3(32, 8), 512, 0, stream>>>(ctx, WoT, bo, x, x1,
                                                       8192, 1024, 1024, 1024);    // x1 (+fp32 x)

  tail_k<<<12288, 256, 0, stream>>>(W2, W2T, x1, g2, be2, h2);                     // W2T + ln2

  gemm256_k<1, 0, 0><<<dim3(32, 16), 512, 0, stream>>>(h2, W1T, b1, nullptr, h3f,
                                                       8192, 4096, 1024, 4096);    // FFN1 + GELU
  gemm256n_k<0, 1, 1><<<dim3(32, 8), 512, 0, stream>>>(h3f, W2T, b2, x1, out,
                                                       8192, 1024, 4096, 1024);    // FFN2 + resid

  (void)in_sizes; (void)n_in; (void)out_size; (void)ws_size;
}